// Round 3
// baseline (2184.273 us; speedup 1.0000x reference)
//
#include <hip/hip_runtime.h>
#include <hip/hip_bf16.h>

#define MROWS 32768
#define NSEQ 4096
#define KDIM 512

typedef short sh8 __attribute__((ext_vector_type(8)));
typedef float fx4 __attribute__((ext_vector_type(4)));

__device__ __forceinline__ unsigned short f2bf(float f) {
  union { float f; unsigned u; } v; v.f = f;
  unsigned r = v.u + 0x7FFFu + ((v.u >> 16) & 1u);
  return (unsigned short)(r >> 16);
}
__device__ __forceinline__ float bf2f(unsigned short u) {
  union { unsigned u; float f; } v; v.u = ((unsigned)u) << 16;
  return v.f;
}

// ---------------------------------------------------------------------------
// bf16 MFMA GEMM: Co[M,Nn] = A[M,512] @ W[Nn,512]^T (+A2@W2^T) (+bias)
// 128x128 tile, BK=32, 256 thr = 4 waves (2x2 of 64x64), mfma 16x16x32.
// A is fp32 (converted in staging) or bf16; W always fp32 (converted).
// ---------------------------------------------------------------------------
template<bool A_BF16, bool OUT_BF16, bool HAS_BIAS, bool TWO>
__global__ __launch_bounds__(256) void gemm_mfma(
    const void* Av, const float* __restrict__ W,
    const void* A2v, const float* __restrict__ W2,
    const float* __restrict__ bias, void* Co, int Nn) {
  __shared__ unsigned short As[128][40];  // pad 40 shorts (80B): 16B-aligned rows
  __shared__ unsigned short Bs[128][40];
  const int tid = threadIdx.x;
  const int lane = tid & 63, wv = tid >> 6;
  const int wr = wv >> 1, wc = wv & 1;
  const int bx = blockIdx.x, by = blockIdx.y;
  const int fr = lane & 15, fg = lane >> 4;
  fx4 acc[4][4] = {};
#pragma unroll
  for (int pass = 0; pass < (TWO ? 2 : 1); ++pass) {
    const float* Wp = (TWO && pass) ? W2 : W;
    const void* Ap = (TWO && pass) ? A2v : Av;
    for (int k0 = 0; k0 < KDIM; k0 += 32) {
      if constexpr (A_BF16) {
        const unsigned short* Ab = (const unsigned short*)Ap;
#pragma unroll
        for (int s = 0; s < 2; ++s) {
          int idx = s * 256 + tid;
          int r = idx >> 2, kq = idx & 3;
          *reinterpret_cast<uint4*>(&As[r][kq * 8]) =
              *reinterpret_cast<const uint4*>(Ab + (size_t)(by * 128 + r) * KDIM + k0 + kq * 8);
        }
      } else {
        const float* Af = (const float*)Ap;
#pragma unroll
        for (int s = 0; s < 4; ++s) {
          int idx = s * 256 + tid;
          int r = idx >> 3, kq = idx & 7;
          float4 v = *reinterpret_cast<const float4*>(
              Af + (size_t)(by * 128 + r) * KDIM + k0 + kq * 4);
          ushort4 o;
          o.x = f2bf(v.x); o.y = f2bf(v.y); o.z = f2bf(v.z); o.w = f2bf(v.w);
          *reinterpret_cast<ushort4*>(&As[r][kq * 4]) = o;
        }
      }
#pragma unroll
      for (int s = 0; s < 4; ++s) {
        int idx = s * 256 + tid;
        int r = idx >> 3, kq = idx & 7;
        float4 v = *reinterpret_cast<const float4*>(
            Wp + (size_t)(bx * 128 + r) * KDIM + k0 + kq * 4);
        ushort4 o;
        o.x = f2bf(v.x); o.y = f2bf(v.y); o.z = f2bf(v.z); o.w = f2bf(v.w);
        *reinterpret_cast<ushort4*>(&Bs[r][kq * 4]) = o;
      }
      __syncthreads();
      sh8 a[4], b[4];
#pragma unroll
      for (int m = 0; m < 4; ++m)
        a[m] = *reinterpret_cast<const sh8*>(&As[wr * 64 + m * 16 + fr][fg * 8]);
#pragma unroll
      for (int n = 0; n < 4; ++n)
        b[n] = *reinterpret_cast<const sh8*>(&Bs[wc * 64 + n * 16 + fr][fg * 8]);
#pragma unroll
      for (int m = 0; m < 4; ++m)
#pragma unroll
        for (int n = 0; n < 4; ++n)
          acc[m][n] = __builtin_amdgcn_mfma_f32_16x16x32_bf16(a[m], b[n], acc[m][n], 0, 0, 0);
      __syncthreads();
    }
  }
  // C/D layout: col = lane&15, row = (lane>>4)*4 + reg
  unsigned short* Cb = (unsigned short*)Co;
  float* Cf = (float*)Co;
#pragma unroll
  for (int n = 0; n < 4; ++n) {
    int col = bx * 128 + wc * 64 + n * 16 + fr;
    float bb = 0.f;
    if constexpr (HAS_BIAS) bb = bias[col];
#pragma unroll
    for (int m = 0; m < 4; ++m) {
#pragma unroll
      for (int j = 0; j < 4; ++j) {
        int row = by * 128 + wr * 64 + m * 16 + fg * 4 + j;
        float val = acc[m][n][j] + bb;
        if constexpr (OUT_BF16)
          Cb[(size_t)row * Nn + col] = f2bf(val);
        else
          Cf[(size_t)row * Nn + col] = val;
      }
    }
  }
}

// ---------------------------------------------------------------------------
// Effective mix weights: W1[h*64+j,c] = sum_i Wmix[j,i]   * Wqkv[h*64+i,c]
//                        W2[h*64+j,c] = sum_i Wmix[j,64+i]* Wqkv[h*64+i,c]
// Also expands bmix[64] -> bmixfull[512] (per-head broadcast).
// ---------------------------------------------------------------------------
__global__ __launch_bounds__(256) void eff_weights(
    const float* __restrict__ Wqkv, const float* __restrict__ Wmix,
    const float* __restrict__ bmix,
    float* __restrict__ W1, float* __restrict__ W2,
    float* __restrict__ bmixfull) {
  int r = blockIdx.x;             // 0..511 output row
  int h = r >> 6, j = r & 63;
  int t = threadIdx.x;
  if (t == 0) bmixfull[r] = bmix[j];
  float a10 = 0.f, a11 = 0.f, a20 = 0.f, a21 = 0.f;
  for (int i = 0; i < 64; ++i) {
    float w1 = Wmix[j * 128 + i], w2 = Wmix[j * 128 + 64 + i];
    const float* wr = Wqkv + (size_t)(h * 64 + i) * KDIM;
    a10 = fmaf(w1, wr[t], a10);
    a11 = fmaf(w1, wr[t + 256], a11);
    a20 = fmaf(w2, wr[t], a20);
    a21 = fmaf(w2, wr[t + 256], a21);
  }
  W1[(size_t)r * KDIM + t] = a10;
  W1[(size_t)r * KDIM + t + 256] = a11;
  W2[(size_t)r * KDIM + t] = a20;
  W2[(size_t)r * KDIM + t + 256] = a21;
}

// ---------------------------------------------------------------------------
// Column softmax stats over sequence dim of k (= kvmat cols 0..511, bf16).
// ---------------------------------------------------------------------------
__global__ __launch_bounds__(256) void ksm_stats_partial(
    const unsigned short* __restrict__ kvmat,
    float* __restrict__ pm, float* __restrict__ ps) {
  int bx = blockIdx.x;
  int split = bx & 15, chunk = (bx >> 4) & 1, b = bx >> 5;
  int c = (chunk << 8) + threadIdx.x;
  const unsigned short* base = kvmat + (size_t)b * NSEQ * 1024 + c;
  int n0 = split << 8;
  float m = -1e30f, s = 0.f;
  for (int n = n0; n < n0 + 256; ++n) {
    float v = bf2f(base[(size_t)n * 1024]);
    if (v > m) { s = s * __expf(m - v) + 1.f; m = v; }
    else       { s += __expf(v - m); }
  }
  pm[((size_t)b * 512 + c) * 16 + split] = m;
  ps[((size_t)b * 512 + c) * 16 + split] = s;
}

__global__ __launch_bounds__(256) void ksm_stats_combine(
    const float* __restrict__ pm, const float* __restrict__ ps,
    float* __restrict__ colmax, float* __restrict__ colsum) {
  int idx = blockIdx.x * 256 + threadIdx.x;  // 0..4095
  float m = -1e30f;
#pragma unroll
  for (int i = 0; i < 16; ++i) m = fmaxf(m, pm[(size_t)idx * 16 + i]);
  float s = 0.f;
#pragma unroll
  for (int i = 0; i < 16; ++i) s += ps[(size_t)idx * 16 + i] * __expf(pm[(size_t)idx * 16 + i] - m);
  colmax[idx] = m;
  colsum[idx] = s;
}

__global__ __launch_bounds__(256) void zero_kv(float* __restrict__ p) {
  int i = (blockIdx.x * 256 + threadIdx.x) * 4;
  *reinterpret_cast<float4*>(p + i) = make_float4(0.f, 0.f, 0.f, 0.f);
}

// ---------------------------------------------------------------------------
// kv[b,h,ck,cv] = sum_n softmax(k)[n,ck] * v[n,cv], scaled by 1/colsum.
// 1024 blocks = (b*8+h)*16 + split; atomicAdd fp32 partials.
// ---------------------------------------------------------------------------
__global__ __launch_bounds__(256) void kv_accum(
    const unsigned short* __restrict__ kvmat, const float* __restrict__ colmax,
    const float* __restrict__ colsum, float* __restrict__ kvbuf) {
  int split = blockIdx.x & 15;
  int bh = blockIdx.x >> 4;
  int h = bh & 7, b = bh >> 3;
  __shared__ float ke[4][64];
  __shared__ float vv[4][64];
  __shared__ float cmx[64], rs[64];
  int t = threadIdx.x;
  if (t < 64) {
    cmx[t] = colmax[b * 512 + h * 64 + t];
    rs[t] = 1.f / colsum[b * 512 + h * 64 + t];
  }
  __syncthreads();
  const unsigned short* kb = kvmat + (size_t)b * NSEQ * 1024 + h * 64;
  const unsigned short* vb = kb + 512;
  int ck = t >> 2, cvb = (t & 3) << 4;
  int nn_ = t >> 6, cc = t & 63;
  float acc[16] = {};
  for (int n0 = split << 8; n0 < (split << 8) + 256; n0 += 4) {
    ke[nn_][cc] = __expf(bf2f(kb[(size_t)(n0 + nn_) * 1024 + cc]) - cmx[cc]);
    vv[nn_][cc] = bf2f(vb[(size_t)(n0 + nn_) * 1024 + cc]);
    __syncthreads();
#pragma unroll
    for (int nn = 0; nn < 4; ++nn) {
      float a = ke[nn][ck];
#pragma unroll
      for (int j = 0; j < 16; ++j) acc[j] = fmaf(a, vv[nn][cvb + j], acc[j]);
    }
    __syncthreads();
  }
  float r = rs[ck];
  float* kvp = kvbuf + ((size_t)(b * 8 + h) * 64 + ck) * 64 + cvb;
#pragma unroll
  for (int j = 0; j < 16; ++j) atomicAdd(&kvp[j], acc[j] * r);
}

// ---------------------------------------------------------------------------
// outpre[row,c] = 0.125*(mq_row . kv[b,h,:,ch]) + qmix * dwconv(v)
// One block per (b,n). Writes bf16 outpre IN PLACE over mqb (own row only).
// ---------------------------------------------------------------------------
__global__ __launch_bounds__(256) void assemble_kernel(
    const unsigned short* __restrict__ kvmat, unsigned short* __restrict__ mqb,
    const unsigned short* __restrict__ qmixb, const float* __restrict__ kvbuf,
    const float* __restrict__ w3, const float* __restrict__ b3,
    const float* __restrict__ w5, const float* __restrict__ b5,
    const float* __restrict__ w7, const float* __restrict__ b7) {
  __shared__ float mqs[512];
  int t = threadIdx.x;
  size_t row = blockIdx.x;
  int n = blockIdx.x & 4095, b = blockIdx.x >> 12;
  int y = n >> 6, x0 = n & 63;
  mqs[t] = bf2f(mqb[row * 512 + t]);
  mqs[t + 256] = bf2f(mqb[row * 512 + t + 256]);
  __syncthreads();
#pragma unroll
  for (int sc = 0; sc < 2; ++sc) {
    int c = t + (sc << 8);
    int h = c >> 6, ch = c & 63;
    const float* kvp = kvbuf + (size_t)(b * 8 + h) * 4096 + ch;
    const float* mh = &mqs[h * 64];
    float fa = 0.f;
#pragma unroll 8
    for (int ck = 0; ck < 64; ++ck)
      fa = fmaf(mh[ck], kvp[(size_t)ck * 64], fa);
    int kw, cl;
    const float *wp, *bp;
    if (c < 128)      { kw = 3; cl = c;       wp = w3; bp = b3; }
    else if (c < 320) { kw = 5; cl = c - 128; wp = w5; bp = b5; }
    else              { kw = 7; cl = c - 320; wp = w7; bp = b7; }
    int p = kw >> 1;
    float conv = bp[cl];
    const unsigned short* vb = kvmat + (size_t)b * NSEQ * 1024 + 512 + c;
    const float* wwr = wp + cl * kw * kw;
    for (int dy = 0; dy < kw; ++dy) {
      int yy = y + dy - p;
      if ((unsigned)yy >= 64u) continue;
      for (int dx = 0; dx < kw; ++dx) {
        int xq = x0 + dx - p;
        if ((unsigned)xq >= 64u) continue;
        conv = fmaf(wwr[dy * kw + dx], bf2f(vb[(size_t)(yy * 64 + xq) * 1024]), conv);
      }
    }
    float qm = bf2f(qmixb[row * 512 + c]);
    float val = 0.125f * fa + qm * conv;
    mqb[row * 512 + c] = f2bf(val);  // outpre in place (own row only)
  }
}

// ---------------------------------------------------------------------------
extern "C" void kernel_launch(void* const* d_in, const int* in_sizes, int n_in,
                              void* d_out, int out_size, void* d_ws, size_t ws_size,
                              hipStream_t stream) {
  const float* x     = (const float*)d_in[0];
  const float* mx    = (const float*)d_in[1];
  const float* Wqkv  = (const float*)d_in[2];
  const float* Wproj = (const float*)d_in[3];
  const float* bproj = (const float*)d_in[4];
  const float* Wmix  = (const float*)d_in[5];
  const float* bmix  = (const float*)d_in[6];
  const float* w3    = (const float*)d_in[7];
  const float* b3    = (const float*)d_in[8];
  const float* w5    = (const float*)d_in[9];
  const float* b5    = (const float*)d_in[10];
  const float* w7    = (const float*)d_in[11];
  const float* b7    = (const float*)d_in[12];

  // kvmat (bf16 [M,1024], k|v) lives in d_out — dead before proj writes out.
  unsigned short* kvmat = (unsigned short*)d_out;

  char* wsp = (char*)d_ws;
  auto carve = [&wsp](size_t bytes) {
    char* p = wsp;
    wsp += (bytes + 255) & ~(size_t)255;
    return p;
  };
  unsigned short* mqb   = (unsigned short*)carve((size_t)MROWS * 512 * 2);  // 33.5 MB
  unsigned short* qmixb = (unsigned short*)carve((size_t)MROWS * 512 * 2);  // 33.5 MB
  float* W1     = (float*)carve(512 * 512 * 4);
  float* W2     = (float*)carve(512 * 512 * 4);
  float* bmixf  = (float*)carve(512 * 4);
  float* kvbuf  = (float*)carve(8 * 8 * 64 * 64 * 4);
  float* colmax = (float*)carve(4096 * 4);
  float* colsum = (float*)carve(4096 * 4);
  float* pm     = (float*)carve(8 * 512 * 16 * 4);
  float* ps     = (float*)carve(8 * 512 * 16 * 4);
  // total ~72 MB

  dim3 blk(256);
  eff_weights<<<dim3(512), blk, 0, stream>>>(Wqkv, Wmix, bmix, W1, W2, bmixf);
  // kvmat = x @ Wqkv[512:1536]^T  -> bf16 [M,1024]
  gemm_mfma<false, true, false, false><<<dim3(8, 256), blk, 0, stream>>>(
      x, Wqkv + (size_t)512 * 512, nullptr, nullptr, nullptr, kvmat, 1024);
  // mqb = mx @ Wqkv[0:512]^T -> bf16 [M,512]
  gemm_mfma<false, true, false, false><<<dim3(4, 256), blk, 0, stream>>>(
      mx, Wqkv, nullptr, nullptr, nullptr, mqb, 512);
  // qmixb = mx @ W1^T + x @ W2^T + bmix -> bf16 [M,512]
  gemm_mfma<false, true, true, true><<<dim3(4, 256), blk, 0, stream>>>(
      mx, W1, x, W2, bmixf, qmixb, 512);
  zero_kv<<<dim3(256), blk, 0, stream>>>(kvbuf);
  ksm_stats_partial<<<dim3(256), blk, 0, stream>>>(kvmat, pm, ps);
  ksm_stats_combine<<<dim3(16), blk, 0, stream>>>(pm, ps, colmax, colsum);
  kv_accum<<<dim3(1024), blk, 0, stream>>>(kvmat, colmax, colsum, kvbuf);
  assemble_kernel<<<dim3(MROWS), blk, 0, stream>>>(
      kvmat, mqb, qmixb, kvbuf, w3, b3, w5, b5, w7, b7);
  // out = outpre @ Wproj^T + bproj  (overwrites kvmat region, now dead)
  gemm_mfma<true, false, true, false><<<dim3(4, 256), blk, 0, stream>>>(
      mqb, Wproj, nullptr, nullptr, bproj, d_out, 512);
}

// Round 5
// 863.263 us; speedup vs baseline: 2.5303x; 2.5303x over previous
//
#include <hip/hip_runtime.h>
#include <hip/hip_bf16.h>

#define MROWS 32768
#define NSEQ 4096
#define KDIM 512

typedef short sh8 __attribute__((ext_vector_type(8)));
typedef float fx4 __attribute__((ext_vector_type(4)));

__device__ __forceinline__ unsigned short f2bf(float f) {
  union { float f; unsigned u; } v; v.f = f;
  unsigned r = v.u + 0x7FFFu + ((v.u >> 16) & 1u);
  return (unsigned short)(r >> 16);
}
__device__ __forceinline__ float bf2f(unsigned short u) {
  union { unsigned u; float f; } v; v.u = ((unsigned)u) << 16;
  return v.f;
}

// ---------------------------------------------------------------------------
// bf16 MFMA GEMM: Co[M,Nn] = A@W^T (+ A2@W2^T) (+bias)
// 128x128 tile, BK=32, 256 thr = 4 waves (2x2 of 64x64), mfma 16x16x32.
// PER_B2: pass-2 weight indexed per batch b = by>>5 (4096-row slabs).
// ---------------------------------------------------------------------------
template<bool A_BF16, bool OUT_BF16, bool HAS_BIAS, bool TWO, bool PER_B2, bool W2_BF16>
__global__ __launch_bounds__(256) void gemm_mfma(
    const void* Av, const float* __restrict__ W,
    const void* A2v, const void* W2v,
    const float* __restrict__ bias, void* Co, int Nn) {
  __shared__ unsigned short As[128][40];
  __shared__ unsigned short Bs[128][40];
  const int tid = threadIdx.x;
  const int lane = tid & 63, wv = tid >> 6;
  const int wr = wv >> 1, wc = wv & 1;
  const int bx = blockIdx.x, by = blockIdx.y;
  const int fr = lane & 15, fg = lane >> 4;
  fx4 acc[4][4] = {};
#pragma unroll
  for (int pass = 0; pass < (TWO ? 2 : 1); ++pass) {
    const void* Ap = (TWO && pass) ? A2v : Av;
    for (int k0 = 0; k0 < KDIM; k0 += 32) {
      // ---- stage A tile ----
      if constexpr (A_BF16) {
        const unsigned short* Ab = (const unsigned short*)Ap;
#pragma unroll
        for (int s = 0; s < 2; ++s) {
          int idx = s * 256 + tid;
          int r = idx >> 2, kq = idx & 3;
          *reinterpret_cast<uint4*>(&As[r][kq * 8]) =
              *reinterpret_cast<const uint4*>(Ab + (size_t)(by * 128 + r) * KDIM + k0 + kq * 8);
        }
      } else {
        const float* Af = (const float*)Ap;
#pragma unroll
        for (int s = 0; s < 4; ++s) {
          int idx = s * 256 + tid;
          int r = idx >> 3, kq = idx & 7;
          float4 v = *reinterpret_cast<const float4*>(
              Af + (size_t)(by * 128 + r) * KDIM + k0 + kq * 4);
          ushort4 o;
          o.x = f2bf(v.x); o.y = f2bf(v.y); o.z = f2bf(v.z); o.w = f2bf(v.w);
          *reinterpret_cast<ushort4*>(&As[r][kq * 4]) = o;
        }
      }
      // ---- stage W tile ----
      if (W2_BF16 && TWO && pass) {
        const unsigned short* Wb16 = (const unsigned short*)W2v;
        if constexpr (PER_B2) Wb16 += (size_t)(by >> 5) * KDIM * 512;
#pragma unroll
        for (int s = 0; s < 2; ++s) {
          int idx = s * 256 + tid;
          int r = idx >> 2, kq = idx & 3;
          *reinterpret_cast<uint4*>(&Bs[r][kq * 8]) =
              *reinterpret_cast<const uint4*>(Wb16 + (size_t)(bx * 128 + r) * KDIM + k0 + kq * 8);
        }
      } else {
        const float* Wp = (TWO && pass) ? (const float*)W2v : W;
#pragma unroll
        for (int s = 0; s < 4; ++s) {
          int idx = s * 256 + tid;
          int r = idx >> 3, kq = idx & 7;
          float4 v = *reinterpret_cast<const float4*>(
              Wp + (size_t)(bx * 128 + r) * KDIM + k0 + kq * 4);
          ushort4 o;
          o.x = f2bf(v.x); o.y = f2bf(v.y); o.z = f2bf(v.z); o.w = f2bf(v.w);
          *reinterpret_cast<ushort4*>(&Bs[r][kq * 4]) = o;
        }
      }
      __syncthreads();
      sh8 a[4], b[4];
#pragma unroll
      for (int m = 0; m < 4; ++m)
        a[m] = *reinterpret_cast<const sh8*>(&As[wr * 64 + m * 16 + fr][fg * 8]);
#pragma unroll
      for (int n = 0; n < 4; ++n)
        b[n] = *reinterpret_cast<const sh8*>(&Bs[wc * 64 + n * 16 + fr][fg * 8]);
#pragma unroll
      for (int m = 0; m < 4; ++m)
#pragma unroll
        for (int n = 0; n < 4; ++n)
          acc[m][n] = __builtin_amdgcn_mfma_f32_16x16x32_bf16(a[m], b[n], acc[m][n], 0, 0, 0);
      __syncthreads();
    }
  }
  unsigned short* Cb = (unsigned short*)Co;
  float* Cf = (float*)Co;
#pragma unroll
  for (int n = 0; n < 4; ++n) {
    int col = bx * 128 + wc * 64 + n * 16 + fr;
    float bb = 0.f;
    if constexpr (HAS_BIAS) bb = bias[col];
#pragma unroll
    for (int m = 0; m < 4; ++m) {
#pragma unroll
      for (int j = 0; j < 4; ++j) {
        int row = by * 128 + wr * 64 + m * 16 + fg * 4 + j;
        float val = acc[m][n][j] + bb;
        if constexpr (OUT_BF16)
          Cb[(size_t)row * Nn + col] = f2bf(val);
        else
          Cf[(size_t)row * Nn + col] = val;
      }
    }
  }
}

// ---------------------------------------------------------------------------
// Effective mix weights + bmix broadcast to 512.
// ---------------------------------------------------------------------------
__global__ __launch_bounds__(256) void eff_weights(
    const float* __restrict__ Wqkv, const float* __restrict__ Wmix,
    const float* __restrict__ bmix,
    float* __restrict__ W1, float* __restrict__ W2,
    float* __restrict__ bmixfull) {
  int r = blockIdx.x;
  int h = r >> 6, j = r & 63;
  int t = threadIdx.x;
  if (t == 0) bmixfull[r] = bmix[j];
  float a10 = 0.f, a11 = 0.f, a20 = 0.f, a21 = 0.f;
  for (int i = 0; i < 64; ++i) {
    float w1 = Wmix[j * 128 + i], w2 = Wmix[j * 128 + 64 + i];
    const float* wr = Wqkv + (size_t)(h * 64 + i) * KDIM;
    a10 = fmaf(w1, wr[t], a10);
    a11 = fmaf(w1, wr[t + 256], a11);
    a20 = fmaf(w2, wr[t], a20);
    a21 = fmaf(w2, wr[t + 256], a21);
  }
  W1[(size_t)r * KDIM + t] = a10;
  W1[(size_t)r * KDIM + t + 256] = a11;
  W2[(size_t)r * KDIM + t] = a20;
  W2[(size_t)r * KDIM + t + 256] = a21;
}

// ---------------------------------------------------------------------------
// Transpose conv weights to tap-major: wT[k*k][CG].
// ---------------------------------------------------------------------------
__global__ __launch_bounds__(256) void wtrans(
    const float* __restrict__ w3, const float* __restrict__ w5,
    const float* __restrict__ w7,
    float* __restrict__ wT3, float* __restrict__ wT5, float* __restrict__ wT7) {
  int i = blockIdx.x * 256 + threadIdx.x;  // grid 60 blocks = 15360
  if (i < 1152) {
    int ti = i >> 7, c = i & 127;
    wT3[i] = w3[c * 9 + ti];
  } else if (i < 5952) {
    int j = i - 1152;
    int ti = j / 192, c = j - ti * 192;
    wT5[j] = w5[c * 25 + ti];
  } else {
    int j = i - 5952;
    int ti = j / 192, c = j - ti * 192;
    wT7[j] = w7[c * 49 + ti];
  }
}

// ---------------------------------------------------------------------------
// Column softmax stats over sequence dim of k (kvmat cols 0..511, bf16).
// ---------------------------------------------------------------------------
__global__ __launch_bounds__(256) void ksm_stats_partial(
    const unsigned short* __restrict__ kvmat,
    float* __restrict__ pm, float* __restrict__ ps) {
  int bx = blockIdx.x;
  int split = bx & 31, chunk = (bx >> 5) & 1, b = bx >> 6;
  int c = (chunk << 8) + threadIdx.x;
  const unsigned short* base = kvmat + (size_t)b * NSEQ * 1024 + c;
  int n0 = split << 7;
  float m = -1e30f, s = 0.f;
#pragma unroll 4
  for (int n = n0; n < n0 + 128; ++n) {
    float v = bf2f(base[(size_t)n * 1024]);
    float nm = fmaxf(m, v);
    s = s * __expf(m - nm) + __expf(v - nm);
    m = nm;
  }
  pm[((size_t)b * 512 + c) * 32 + split] = m;
  ps[((size_t)b * 512 + c) * 32 + split] = s;
}

__global__ __launch_bounds__(256) void ksm_stats_combine(
    const float* __restrict__ pm, const float* __restrict__ ps,
    float* __restrict__ colmax, float* __restrict__ colsum) {
  int idx = blockIdx.x * 256 + threadIdx.x;  // 0..4095
  float m = -1e30f;
#pragma unroll
  for (int i = 0; i < 32; ++i) m = fmaxf(m, pm[(size_t)idx * 32 + i]);
  float s = 0.f;
#pragma unroll
  for (int i = 0; i < 32; ++i) s += ps[(size_t)idx * 32 + i] * __expf(pm[(size_t)idx * 32 + i] - m);
  colmax[idx] = m;
  colsum[idx] = s;
}

__global__ __launch_bounds__(256) void zero_kv(float* __restrict__ p) {
  int i = (blockIdx.x * 256 + threadIdx.x) * 4;
  *reinterpret_cast<float4*>(p + i) = make_float4(0.f, 0.f, 0.f, 0.f);
}

// ---------------------------------------------------------------------------
// kv[b,h,ck,cv] = sum_n softmax(k)[n,ck] * v[n,cv], scaled by 1/colsum.
// ---------------------------------------------------------------------------
__global__ __launch_bounds__(256) void kv_accum(
    const unsigned short* __restrict__ kvmat, const float* __restrict__ colmax,
    const float* __restrict__ colsum, float* __restrict__ kvbuf) {
  int split = blockIdx.x & 15;
  int bh = blockIdx.x >> 4;
  int h = bh & 7, b = bh >> 3;
  __shared__ float ke[4][64];
  __shared__ float vv[4][64];
  __shared__ float cmx[64], rs[64];
  int t = threadIdx.x;
  if (t < 64) {
    cmx[t] = colmax[b * 512 + h * 64 + t];
    rs[t] = 1.f / colsum[b * 512 + h * 64 + t];
  }
  __syncthreads();
  const unsigned short* kb = kvmat + (size_t)b * NSEQ * 1024 + h * 64;
  const unsigned short* vb = kb + 512;
  int ck = t >> 2, cvb = (t & 3) << 4;
  int nn_ = t >> 6, cc = t & 63;
  float acc[16] = {};
  for (int n0 = split << 8; n0 < (split << 8) + 256; n0 += 4) {
    ke[nn_][cc] = __expf(bf2f(kb[(size_t)(n0 + nn_) * 1024 + cc]) - cmx[cc]);
    vv[nn_][cc] = bf2f(vb[(size_t)(n0 + nn_) * 1024 + cc]);
    __syncthreads();
#pragma unroll
    for (int nn = 0; nn < 4; ++nn) {
      float a = ke[nn][ck];
#pragma unroll
      for (int j = 0; j < 16; ++j) acc[j] = fmaf(a, vv[nn][cvb + j], acc[j]);
    }
    __syncthreads();
  }
  float r = rs[ck];
  float* kvp = kvbuf + ((size_t)(b * 8 + h) * 64 + ck) * 64 + cvb;
#pragma unroll
  for (int j = 0; j < 16; ++j) atomicAdd(&kvp[j], acc[j] * r);
}

// ---------------------------------------------------------------------------
// Wb[b][j][h*64+ck] = 0.125 * sum_ch kv[b,h,ck,ch] * Wproj[j, h*64+ch]  (bf16)
// grid = ((b*8+h)*16 + jt), 1024 blocks; j0 = jt*32.
// ---------------------------------------------------------------------------
__global__ __launch_bounds__(256) void wproj_eff(
    const float* __restrict__ kvbuf, const float* __restrict__ Wproj,
    unsigned short* __restrict__ Wb) {
  int bid = blockIdx.x;
  int jt = bid & 15, h = (bid >> 4) & 7, b = bid >> 7;
  int j0 = jt * 32;
  __shared__ float kvs[64][65];
  __shared__ float wps[32][64];
  int t = threadIdx.x;
  const float* kvsrc = kvbuf + (size_t)(b * 8 + h) * 4096;
  for (int i = t; i < 4096; i += 256) kvs[i >> 6][i & 63] = kvsrc[i];
  for (int i = t; i < 2048; i += 256)
    wps[i >> 6][i & 63] = Wproj[(size_t)(j0 + (i >> 6)) * 512 + h * 64 + (i & 63)];
  __syncthreads();
  int ck = t & 63, jl = t >> 6;  // jl 0..3
  float acc[8] = {};
  for (int ch = 0; ch < 64; ++ch) {
    float kvv = kvs[ck][ch];
#pragma unroll
    for (int g = 0; g < 8; ++g)
      acc[g] = fmaf(kvv, wps[jl * 8 + g][ch], acc[g]);
  }
#pragma unroll
  for (int g = 0; g < 8; ++g)
    Wb[((size_t)b * 512 + j0 + jl * 8 + g) * 512 + h * 64 + ck] = f2bf(0.125f * acc[g]);
}

// ---------------------------------------------------------------------------
// Depthwise conv + crpe multiply, vectorized 8 channels/thread.
// crpe[row, c0..c0+8] = qmix * (bias + sum taps w*v); overwrites qmixb.
// ---------------------------------------------------------------------------
template<int KW, int C0, int CG, int TPB>
__global__ __launch_bounds__(TPB) void conv_crpe(
    const unsigned short* __restrict__ kvmat,
    unsigned short* __restrict__ qmixb,
    const float* __restrict__ wT, const float* __restrict__ bias) {
  constexpr int SLOTS = CG / 8;
  constexpr int ROWS_PB = TPB / SLOTS;
  constexpr int P = KW / 2;
  int t = threadIdx.x;
  int row_local = t / SLOTS;
  int slot = t - row_local * SLOTS;
  int row = blockIdx.x * ROWS_PB + row_local;
  int n = row & 4095, b = row >> 12;
  int y = n >> 6, x = n & 63;
  int cl = slot * 8;  // local channel base within group
  float acc[8] = {};
  const unsigned short* vb =
      kvmat + (size_t)b * NSEQ * 1024 + 512 + C0 + cl;
#pragma unroll
  for (int dy = 0; dy < KW; ++dy) {
    int yy = y + dy - P;
    if ((unsigned)yy >= 64u) continue;
#pragma unroll
    for (int dx = 0; dx < KW; ++dx) {
      int xq = x + dx - P;
      if ((unsigned)xq >= 64u) continue;
      sh8 v8 = *reinterpret_cast<const sh8*>(vb + (size_t)(yy * 64 + xq) * 1024);
      const float* wp = wT + (dy * KW + dx) * CG + cl;
      float4 w0 = *reinterpret_cast<const float4*>(wp);
      float4 w1 = *reinterpret_cast<const float4*>(wp + 4);
      acc[0] = fmaf(w0.x, bf2f((unsigned short)v8[0]), acc[0]);
      acc[1] = fmaf(w0.y, bf2f((unsigned short)v8[1]), acc[1]);
      acc[2] = fmaf(w0.z, bf2f((unsigned short)v8[2]), acc[2]);
      acc[3] = fmaf(w0.w, bf2f((unsigned short)v8[3]), acc[3]);
      acc[4] = fmaf(w1.x, bf2f((unsigned short)v8[4]), acc[4]);
      acc[5] = fmaf(w1.y, bf2f((unsigned short)v8[5]), acc[5]);
      acc[6] = fmaf(w1.z, bf2f((unsigned short)v8[6]), acc[6]);
      acc[7] = fmaf(w1.w, bf2f((unsigned short)v8[7]), acc[7]);
    }
  }
  float4 b0 = *reinterpret_cast<const float4*>(bias + cl);
  float4 b1 = *reinterpret_cast<const float4*>(bias + cl + 4);
  unsigned short* qp = qmixb + (size_t)row * 512 + C0 + cl;
  sh8 qm = *reinterpret_cast<const sh8*>(qp);
  sh8 out;
  out[0] = (short)f2bf(bf2f((unsigned short)qm[0]) * (acc[0] + b0.x));
  out[1] = (short)f2bf(bf2f((unsigned short)qm[1]) * (acc[1] + b0.y));
  out[2] = (short)f2bf(bf2f((unsigned short)qm[2]) * (acc[2] + b0.z));
  out[3] = (short)f2bf(bf2f((unsigned short)qm[3]) * (acc[3] + b0.w));
  out[4] = (short)f2bf(bf2f((unsigned short)qm[4]) * (acc[4] + b1.x));
  out[5] = (short)f2bf(bf2f((unsigned short)qm[5]) * (acc[5] + b1.y));
  out[6] = (short)f2bf(bf2f((unsigned short)qm[6]) * (acc[6] + b1.z));
  out[7] = (short)f2bf(bf2f((unsigned short)qm[7]) * (acc[7] + b1.w));
  *reinterpret_cast<sh8*>(qp) = out;
}

// ---------------------------------------------------------------------------
extern "C" void kernel_launch(void* const* d_in, const int* in_sizes, int n_in,
                              void* d_out, int out_size, void* d_ws, size_t ws_size,
                              hipStream_t stream) {
  const float* x     = (const float*)d_in[0];
  const float* mx    = (const float*)d_in[1];
  const float* Wqkv  = (const float*)d_in[2];
  const float* Wproj = (const float*)d_in[3];
  const float* bproj = (const float*)d_in[4];
  const float* Wmix  = (const float*)d_in[5];
  const float* bmix  = (const float*)d_in[6];
  const float* w3    = (const float*)d_in[7];
  const float* b3    = (const float*)d_in[8];
  const float* w5    = (const float*)d_in[9];
  const float* b5    = (const float*)d_in[10];
  const float* w7    = (const float*)d_in[11];
  const float* b7    = (const float*)d_in[12];

  // kvmat (bf16 [M,1024], k|v) lives in d_out — dead before proj writes out.
  unsigned short* kvmat = (unsigned short*)d_out;

  char* wsp = (char*)d_ws;
  auto carve = [&wsp](size_t bytes) {
    char* p = wsp;
    wsp += (bytes + 255) & ~(size_t)255;
    return p;
  };
  unsigned short* mqb   = (unsigned short*)carve((size_t)MROWS * 512 * 2);  // 33.5 MB
  unsigned short* qmixb = (unsigned short*)carve((size_t)MROWS * 512 * 2);  // 33.5 MB
  float* W1     = (float*)carve(512 * 512 * 4);
  float* W2     = (float*)carve(512 * 512 * 4);
  float* bmixf  = (float*)carve(512 * 4);
  float* kvbuf  = (float*)carve(8 * 8 * 64 * 64 * 4);
  float* colmax = (float*)carve(4096 * 4);
  float* colsum = (float*)carve(4096 * 4);
  float* wT3    = (float*)carve(9 * 128 * 4);
  float* wT5    = (float*)carve(25 * 192 * 4);
  float* wT7    = (float*)carve(49 * 192 * 4);
  // Overlay region: pm/ps (stats partials, dead after combine) then Wb.
  char* R = (char*)carve(8 * 512 * 512 * 2);  // 4.2 MB
  float* pm = (float*)R;                        // 4096*32*4 = 512 KB
  float* ps = (float*)(R + 4096 * 32 * 4);      // 512 KB
  unsigned short* Wb = (unsigned short*)R;      // 8*512*512 bf16 (after combine)

  dim3 blk(256);
  eff_weights<<<dim3(512), blk, 0, stream>>>(Wqkv, Wmix, bmix, W1, W2, bmixf);
  wtrans<<<dim3(60), blk, 0, stream>>>(w3, w5, w7, wT3, wT5, wT7);
  // kvmat = x @ Wqkv[512:1536]^T -> bf16 [M,1024]
  gemm_mfma<false, true, false, false, false, false><<<dim3(8, 256), blk, 0, stream>>>(
      x, Wqkv + (size_t)512 * 512, nullptr, nullptr, nullptr, kvmat, 1024);
  // mqb = mx @ Wqkv[0:512]^T -> bf16 [M,512]
  gemm_mfma<false, true, false, false, false, false><<<dim3(4, 256), blk, 0, stream>>>(
      mx, Wqkv, nullptr, nullptr, nullptr, mqb, 512);
  // qmixb = mx @ W1^T + x @ W2^T + bmix -> bf16 [M,512]
  gemm_mfma<false, true, true, true, false, false><<<dim3(4, 256), blk, 0, stream>>>(
      mx, W1, x, W2, bmixf, qmixb, 512);
  zero_kv<<<dim3(256), blk, 0, stream>>>(kvbuf);
  ksm_stats_partial<<<dim3(512), blk, 0, stream>>>(kvmat, pm, ps);
  ksm_stats_combine<<<dim3(16), blk, 0, stream>>>(pm, ps, colmax, colsum);
  kv_accum<<<dim3(1024), blk, 0, stream>>>(kvmat, colmax, colsum, kvbuf);
  // Wb[b] = 0.125 * blockdiag(kv[b]) @ Wproj^T   (bf16, overlays pm/ps)
  wproj_eff<<<dim3(1024), blk, 0, stream>>>(kvbuf, Wproj, Wb);
  // crpe = qmix * dwconv(v), in place over qmixb
  conv_crpe<3, 0, 128, 256><<<dim3(2048), dim3(256), 0, stream>>>(kvmat, qmixb, wT3, b3);
  conv_crpe<5, 128, 192, 192><<<dim3(4096), dim3(192), 0, stream>>>(kvmat, qmixb, wT5, b5);
  conv_crpe<7, 320, 192, 192><<<dim3(4096), dim3(192), 0, stream>>>(kvmat, qmixb, wT7, b7);
  // out = crpe @ Wproj^T + mq @ Wb[b]^T + bproj
  gemm_mfma<true, false, true, true, true, true><<<dim3(4, 256), blk, 0, stream>>>(
      qmixb, Wproj, mqb, Wb, bproj, d_out, 512);
}

// Round 6
// 617.981 us; speedup vs baseline: 3.5345x; 1.3969x over previous
//
#include <hip/hip_runtime.h>
#include <hip/hip_bf16.h>

#define MROWS 32768
#define NSEQ 4096
#define KDIM 512

typedef short sh8 __attribute__((ext_vector_type(8)));
typedef float fx4 __attribute__((ext_vector_type(4)));

__device__ __forceinline__ unsigned short f2bf(float f) {
  union { float f; unsigned u; } v; v.f = f;
  unsigned r = v.u + 0x7FFFu + ((v.u >> 16) & 1u);
  return (unsigned short)(r >> 16);
}
__device__ __forceinline__ float bf2f(unsigned short u) {
  union { unsigned u; float f; } v; v.u = ((unsigned)u) << 16;
  return v.f;
}

// ---------------------------------------------------------------------------
// bf16 MFMA GEMM: Co[M,Nn] = A@W^T (+ A2@W2^T) (+bias)
// 128x128 tile, BK=32, 256 thr = 4 waves (2x2 of 64x64), mfma 16x16x32.
// PER_B2: pass-2 weight indexed per batch b = by>>5 (4096-row slabs).
// ---------------------------------------------------------------------------
template<bool A_BF16, bool OUT_BF16, bool HAS_BIAS, bool TWO, bool PER_B2, bool W2_BF16>
__global__ __launch_bounds__(256) void gemm_mfma(
    const void* Av, const float* __restrict__ W,
    const void* A2v, const void* W2v,
    const float* __restrict__ bias, void* Co, int Nn) {
  __shared__ unsigned short As[128][40];
  __shared__ unsigned short Bs[128][40];
  const int tid = threadIdx.x;
  const int lane = tid & 63, wv = tid >> 6;
  const int wr = wv >> 1, wc = wv & 1;
  const int bx = blockIdx.x, by = blockIdx.y;
  const int fr = lane & 15, fg = lane >> 4;
  fx4 acc[4][4] = {};
#pragma unroll
  for (int pass = 0; pass < (TWO ? 2 : 1); ++pass) {
    const void* Ap = (TWO && pass) ? A2v : Av;
    for (int k0 = 0; k0 < KDIM; k0 += 32) {
      // ---- stage A tile ----
      if constexpr (A_BF16) {
        const unsigned short* Ab = (const unsigned short*)Ap;
#pragma unroll
        for (int s = 0; s < 2; ++s) {
          int idx = s * 256 + tid;
          int r = idx >> 2, kq = idx & 3;
          *reinterpret_cast<uint4*>(&As[r][kq * 8]) =
              *reinterpret_cast<const uint4*>(Ab + (size_t)(by * 128 + r) * KDIM + k0 + kq * 8);
        }
      } else {
        const float* Af = (const float*)Ap;
#pragma unroll
        for (int s = 0; s < 4; ++s) {
          int idx = s * 256 + tid;
          int r = idx >> 3, kq = idx & 7;
          float4 v = *reinterpret_cast<const float4*>(
              Af + (size_t)(by * 128 + r) * KDIM + k0 + kq * 4);
          ushort4 o;
          o.x = f2bf(v.x); o.y = f2bf(v.y); o.z = f2bf(v.z); o.w = f2bf(v.w);
          *reinterpret_cast<ushort4*>(&As[r][kq * 4]) = o;
        }
      }
      // ---- stage W tile ----
      if (W2_BF16 && TWO && pass) {
        const unsigned short* Wb16 = (const unsigned short*)W2v;
        if constexpr (PER_B2) Wb16 += (size_t)(by >> 5) * KDIM * 512;
#pragma unroll
        for (int s = 0; s < 2; ++s) {
          int idx = s * 256 + tid;
          int r = idx >> 2, kq = idx & 3;
          *reinterpret_cast<uint4*>(&Bs[r][kq * 8]) =
              *reinterpret_cast<const uint4*>(Wb16 + (size_t)(bx * 128 + r) * KDIM + k0 + kq * 8);
        }
      } else {
        const float* Wp = (TWO && pass) ? (const float*)W2v : W;
#pragma unroll
        for (int s = 0; s < 4; ++s) {
          int idx = s * 256 + tid;
          int r = idx >> 3, kq = idx & 7;
          float4 v = *reinterpret_cast<const float4*>(
              Wp + (size_t)(bx * 128 + r) * KDIM + k0 + kq * 4);
          ushort4 o;
          o.x = f2bf(v.x); o.y = f2bf(v.y); o.z = f2bf(v.z); o.w = f2bf(v.w);
          *reinterpret_cast<ushort4*>(&Bs[r][kq * 4]) = o;
        }
      }
      __syncthreads();
      sh8 a[4], b[4];
#pragma unroll
      for (int m = 0; m < 4; ++m)
        a[m] = *reinterpret_cast<const sh8*>(&As[wr * 64 + m * 16 + fr][fg * 8]);
#pragma unroll
      for (int n = 0; n < 4; ++n)
        b[n] = *reinterpret_cast<const sh8*>(&Bs[wc * 64 + n * 16 + fr][fg * 8]);
#pragma unroll
      for (int m = 0; m < 4; ++m)
#pragma unroll
        for (int n = 0; n < 4; ++n)
          acc[m][n] = __builtin_amdgcn_mfma_f32_16x16x32_bf16(a[m], b[n], acc[m][n], 0, 0, 0);
      __syncthreads();
    }
  }
  unsigned short* Cb = (unsigned short*)Co;
  float* Cf = (float*)Co;
#pragma unroll
  for (int n = 0; n < 4; ++n) {
    int col = bx * 128 + wc * 64 + n * 16 + fr;
    float bb = 0.f;
    if constexpr (HAS_BIAS) bb = bias[col];
#pragma unroll
    for (int m = 0; m < 4; ++m) {
#pragma unroll
      for (int j = 0; j < 4; ++j) {
        int row = by * 128 + wr * 64 + m * 16 + fg * 4 + j;
        float val = acc[m][n][j] + bb;
        if constexpr (OUT_BF16)
          Cb[(size_t)row * Nn + col] = f2bf(val);
        else
          Cf[(size_t)row * Nn + col] = val;
      }
    }
  }
}

// ---------------------------------------------------------------------------
// Effective mix weights + bmix broadcast to 512.
// ---------------------------------------------------------------------------
__global__ __launch_bounds__(256) void eff_weights(
    const float* __restrict__ Wqkv, const float* __restrict__ Wmix,
    const float* __restrict__ bmix,
    float* __restrict__ W1, float* __restrict__ W2,
    float* __restrict__ bmixfull) {
  int r = blockIdx.x;
  int h = r >> 6, j = r & 63;
  int t = threadIdx.x;
  if (t == 0) bmixfull[r] = bmix[j];
  float a10 = 0.f, a11 = 0.f, a20 = 0.f, a21 = 0.f;
  for (int i = 0; i < 64; ++i) {
    float w1 = Wmix[j * 128 + i], w2 = Wmix[j * 128 + 64 + i];
    const float* wr = Wqkv + (size_t)(h * 64 + i) * KDIM;
    a10 = fmaf(w1, wr[t], a10);
    a11 = fmaf(w1, wr[t + 256], a11);
    a20 = fmaf(w2, wr[t], a20);
    a21 = fmaf(w2, wr[t + 256], a21);
  }
  W1[(size_t)r * KDIM + t] = a10;
  W1[(size_t)r * KDIM + t + 256] = a11;
  W2[(size_t)r * KDIM + t] = a20;
  W2[(size_t)r * KDIM + t + 256] = a21;
}

// ---------------------------------------------------------------------------
// Transpose conv weights to tap-major: wT[k*k][CG].
// ---------------------------------------------------------------------------
__global__ __launch_bounds__(256) void wtrans(
    const float* __restrict__ w3, const float* __restrict__ w5,
    const float* __restrict__ w7,
    float* __restrict__ wT3, float* __restrict__ wT5, float* __restrict__ wT7) {
  int i = blockIdx.x * 256 + threadIdx.x;
  if (i < 1152) {
    int ti = i >> 7, c = i & 127;
    wT3[i] = w3[c * 9 + ti];
  } else if (i < 5952) {
    int j = i - 1152;
    int ti = j / 192, c = j - ti * 192;
    wT5[j] = w5[c * 25 + ti];
  } else {
    int j = i - 5952;
    int ti = j / 192, c = j - ti * 192;
    wT7[j] = w7[c * 49 + ti];
  }
}

__global__ __launch_bounds__(256) void zero_colsum(float* __restrict__ p) {
  int i = (blockIdx.x * 256 + threadIdx.x) * 4;
  *reinterpret_cast<float4*>(p + i) = make_float4(0.f, 0.f, 0.f, 0.f);
}

// ---------------------------------------------------------------------------
// kv partials via MFMA: kvpart[split][bh][ck][cv] = sum_n exp(k[n,ck])*v[n,cv]
// over this block's n-range. No max subtraction (|k| small). colsum (sum of
// exp) accumulated in-register, shuffle-reduced, one 64-atomic burst/block.
// Grid = 512 blocks: blockIdx = bh*8 + split. 256 thr = 4 waves (2x2 of 32x32).
// LDS transposed with XOR block swizzle: col' = n ^ (((ch>>3)&3)<<3).
// ---------------------------------------------------------------------------
__global__ __launch_bounds__(256) void kv_mfma(
    const unsigned short* __restrict__ kvmat,
    float* __restrict__ kvpart, float* __restrict__ colsum) {
  __shared__ unsigned short eK[64][40];  // rows 80B (16B-aligned)
  __shared__ unsigned short eV[64][40];
  __shared__ float cw[4][64];
  int t = threadIdx.x;
  int split = blockIdx.x & 7;
  int bh = blockIdx.x >> 3;
  int h = bh & 7, b = bh >> 3;
  int lane = t & 63, wv = t >> 6;
  int wr = wv >> 1, wc = wv & 1;
  int fr = lane & 15, fg = lane >> 4;
  int cg = t & 7, nl = t >> 3;  // staging: ch-group 0..7, n-local 0..31
  const unsigned short* kb = kvmat + (size_t)b * NSEQ * 1024 + h * 64 + cg * 8;
  const unsigned short* vb = kb + 512;
  int colS = nl ^ ((cg & 3) << 3);  // swizzled column for this thread's writes
  fx4 acc[2][2] = {};
  float csum[8] = {};
  for (int n0 = split * 512; n0 < split * 512 + 512; n0 += 32) {
    size_t off = (size_t)(n0 + nl) * 1024;
    sh8 k8 = *reinterpret_cast<const sh8*>(kb + off);
    sh8 v8 = *reinterpret_cast<const sh8*>(vb + off);
#pragma unroll
    for (int j = 0; j < 8; ++j) {
      float e = __expf(bf2f((unsigned short)k8[j]));
      csum[j] += e;
      eK[cg * 8 + j][colS] = f2bf(e);
      eV[cg * 8 + j][colS] = (unsigned short)v8[j];
    }
    __syncthreads();
    sh8 a[2], bb[2];
#pragma unroll
    for (int m = 0; m < 2; ++m) {
      int r = wr * 32 + m * 16 + fr;
      int c8 = (fg ^ ((r >> 3) & 3)) * 8;
      a[m] = *reinterpret_cast<const sh8*>(&eK[r][c8]);
    }
#pragma unroll
    for (int n = 0; n < 2; ++n) {
      int r = wc * 32 + n * 16 + fr;
      int c8 = (fg ^ ((r >> 3) & 3)) * 8;
      bb[n] = *reinterpret_cast<const sh8*>(&eV[r][c8]);
    }
#pragma unroll
    for (int m = 0; m < 2; ++m)
#pragma unroll
      for (int n = 0; n < 2; ++n)
        acc[m][n] = __builtin_amdgcn_mfma_f32_16x16x32_bf16(a[m], bb[n], acc[m][n], 0, 0, 0);
    __syncthreads();
  }
  // write per-split partial (no atomics)
  float* kvp = kvpart + (size_t)split * 64 * 4096 + (size_t)bh * 4096;
#pragma unroll
  for (int m = 0; m < 2; ++m)
#pragma unroll
    for (int n = 0; n < 2; ++n)
#pragma unroll
      for (int j = 0; j < 4; ++j) {
        int row = wr * 32 + m * 16 + fg * 4 + j;
        int col = wc * 32 + n * 16 + fr;
        kvp[row * 64 + col] = acc[m][n][j];
      }
  // colsum: reduce over lanes sharing lane&7 (stride-8 groups)
#pragma unroll
  for (int j = 0; j < 8; ++j) {
    float v = csum[j];
    v += __shfl_xor(v, 8);
    v += __shfl_xor(v, 16);
    v += __shfl_xor(v, 32);
    csum[j] = v;
  }
  if (lane < 8) {
#pragma unroll
    for (int j = 0; j < 8; ++j) cw[wv][lane * 8 + j] = csum[j];
  }
  __syncthreads();
  if (t < 64) {
    float s = cw[0][t] + cw[1][t] + cw[2][t] + cw[3][t];
    atomicAdd(&colsum[b * 512 + h * 64 + t], s);
  }
}

// kvbuf[i] = sum over 8 splits of kvpart[s][i]; i over 64*4096 floats.
__global__ __launch_bounds__(256) void kv_reduce(
    const float* __restrict__ kvpart, float* __restrict__ kvbuf) {
  int i = (blockIdx.x * 256 + threadIdx.x) * 4;
  float4 s = make_float4(0.f, 0.f, 0.f, 0.f);
#pragma unroll
  for (int sp = 0; sp < 8; ++sp) {
    float4 v = *reinterpret_cast<const float4*>(kvpart + (size_t)sp * 262144 + i);
    s.x += v.x; s.y += v.y; s.z += v.z; s.w += v.w;
  }
  *reinterpret_cast<float4*>(kvbuf + i) = s;
}

// ---------------------------------------------------------------------------
// Wb[b][j][h*64+ck] = 0.125/colsum[ck] * sum_ch kv[b,h,ck,ch]*Wproj[j,h*64+ch]
// ---------------------------------------------------------------------------
__global__ __launch_bounds__(256) void wproj_eff(
    const float* __restrict__ kvbuf, const float* __restrict__ Wproj,
    const float* __restrict__ colsum, unsigned short* __restrict__ Wb) {
  int bid = blockIdx.x;
  int jt = bid & 15, h = (bid >> 4) & 7, b = bid >> 7;
  int j0 = jt * 32;
  __shared__ float kvs[64][65];
  __shared__ float wps[32][64];
  int t = threadIdx.x;
  const float* kvsrc = kvbuf + (size_t)(b * 8 + h) * 4096;
  for (int i = t; i < 4096; i += 256) kvs[i >> 6][i & 63] = kvsrc[i];
  for (int i = t; i < 2048; i += 256)
    wps[i >> 6][i & 63] = Wproj[(size_t)(j0 + (i >> 6)) * 512 + h * 64 + (i & 63)];
  __syncthreads();
  int ck = t & 63, jl = t >> 6;
  float rs = 0.125f / colsum[b * 512 + h * 64 + ck];
  float acc[8] = {};
  for (int ch = 0; ch < 64; ++ch) {
    float kvv = kvs[ck][ch];
#pragma unroll
    for (int g = 0; g < 8; ++g)
      acc[g] = fmaf(kvv, wps[jl * 8 + g][ch], acc[g]);
  }
#pragma unroll
  for (int g = 0; g < 8; ++g)
    Wb[((size_t)b * 512 + j0 + jl * 8 + g) * 512 + h * 64 + ck] = f2bf(rs * acc[g]);
}

// ---------------------------------------------------------------------------
// Depthwise conv + crpe multiply, vectorized 8 channels/thread.
// ---------------------------------------------------------------------------
template<int KW, int C0, int CG, int TPB>
__global__ __launch_bounds__(TPB) void conv_crpe(
    const unsigned short* __restrict__ kvmat,
    unsigned short* __restrict__ qmixb,
    const float* __restrict__ wT, const float* __restrict__ bias) {
  constexpr int SLOTS = CG / 8;
  constexpr int ROWS_PB = TPB / SLOTS;
  constexpr int P = KW / 2;
  int t = threadIdx.x;
  int row_local = t / SLOTS;
  int slot = t - row_local * SLOTS;
  int row = blockIdx.x * ROWS_PB + row_local;
  int n = row & 4095, b = row >> 12;
  int y = n >> 6, x = n & 63;
  int cl = slot * 8;
  float acc[8] = {};
  const unsigned short* vb =
      kvmat + (size_t)b * NSEQ * 1024 + 512 + C0 + cl;
#pragma unroll
  for (int dy = 0; dy < KW; ++dy) {
    int yy = y + dy - P;
    if ((unsigned)yy >= 64u) continue;
#pragma unroll
    for (int dx = 0; dx < KW; ++dx) {
      int xq = x + dx - P;
      if ((unsigned)xq >= 64u) continue;
      sh8 v8 = *reinterpret_cast<const sh8*>(vb + (size_t)(yy * 64 + xq) * 1024);
      const float* wp = wT + (dy * KW + dx) * CG + cl;
      float4 w0 = *reinterpret_cast<const float4*>(wp);
      float4 w1 = *reinterpret_cast<const float4*>(wp + 4);
      acc[0] = fmaf(w0.x, bf2f((unsigned short)v8[0]), acc[0]);
      acc[1] = fmaf(w0.y, bf2f((unsigned short)v8[1]), acc[1]);
      acc[2] = fmaf(w0.z, bf2f((unsigned short)v8[2]), acc[2]);
      acc[3] = fmaf(w0.w, bf2f((unsigned short)v8[3]), acc[3]);
      acc[4] = fmaf(w1.x, bf2f((unsigned short)v8[4]), acc[4]);
      acc[5] = fmaf(w1.y, bf2f((unsigned short)v8[5]), acc[5]);
      acc[6] = fmaf(w1.z, bf2f((unsigned short)v8[6]), acc[6]);
      acc[7] = fmaf(w1.w, bf2f((unsigned short)v8[7]), acc[7]);
    }
  }
  float4 b0 = *reinterpret_cast<const float4*>(bias + cl);
  float4 b1 = *reinterpret_cast<const float4*>(bias + cl + 4);
  unsigned short* qp = qmixb + (size_t)row * 512 + C0 + cl;
  sh8 qm = *reinterpret_cast<const sh8*>(qp);
  sh8 out;
  out[0] = (short)f2bf(bf2f((unsigned short)qm[0]) * (acc[0] + b0.x));
  out[1] = (short)f2bf(bf2f((unsigned short)qm[1]) * (acc[1] + b0.y));
  out[2] = (short)f2bf(bf2f((unsigned short)qm[2]) * (acc[2] + b0.z));
  out[3] = (short)f2bf(bf2f((unsigned short)qm[3]) * (acc[3] + b0.w));
  out[4] = (short)f2bf(bf2f((unsigned short)qm[4]) * (acc[4] + b1.x));
  out[5] = (short)f2bf(bf2f((unsigned short)qm[5]) * (acc[5] + b1.y));
  out[6] = (short)f2bf(bf2f((unsigned short)qm[6]) * (acc[6] + b1.z));
  out[7] = (short)f2bf(bf2f((unsigned short)qm[7]) * (acc[7] + b1.w));
  *reinterpret_cast<sh8*>(qp) = out;
}

// ---------------------------------------------------------------------------
extern "C" void kernel_launch(void* const* d_in, const int* in_sizes, int n_in,
                              void* d_out, int out_size, void* d_ws, size_t ws_size,
                              hipStream_t stream) {
  const float* x     = (const float*)d_in[0];
  const float* mx    = (const float*)d_in[1];
  const float* Wqkv  = (const float*)d_in[2];
  const float* Wproj = (const float*)d_in[3];
  const float* bproj = (const float*)d_in[4];
  const float* Wmix  = (const float*)d_in[5];
  const float* bmix  = (const float*)d_in[6];
  const float* w3    = (const float*)d_in[7];
  const float* b3    = (const float*)d_in[8];
  const float* w5    = (const float*)d_in[9];
  const float* b5    = (const float*)d_in[10];
  const float* w7    = (const float*)d_in[11];
  const float* b7    = (const float*)d_in[12];

  // kvmat (bf16 [M,1024], k|v) lives in d_out — dead before proj writes out.
  unsigned short* kvmat = (unsigned short*)d_out;

  char* wsp = (char*)d_ws;
  auto carve = [&wsp](size_t bytes) {
    char* p = wsp;
    wsp += (bytes + 255) & ~(size_t)255;
    return p;
  };
  unsigned short* mqb   = (unsigned short*)carve((size_t)MROWS * 512 * 2);  // 33.5 MB
  unsigned short* qmixb = (unsigned short*)carve((size_t)MROWS * 512 * 2);  // 33.5 MB
  float* W1     = (float*)carve(512 * 512 * 4);
  float* W2     = (float*)carve(512 * 512 * 4);
  float* bmixf  = (float*)carve(512 * 4);
  float* kvbuf  = (float*)carve(8 * 8 * 64 * 64 * 4);   // 1 MB
  float* colsum = (float*)carve(4096 * 4);
  float* wT3    = (float*)carve(9 * 128 * 4);
  float* wT5    = (float*)carve(25 * 192 * 4);
  float* wT7    = (float*)carve(49 * 192 * 4);
  float* kvpart = (float*)carve((size_t)8 * 64 * 4096 * 4);  // 8 MB
  unsigned short* Wb = (unsigned short*)carve((size_t)8 * 512 * 512 * 2);  // 4.2 MB
  // total ~81 MB

  dim3 blk(256);
  eff_weights<<<dim3(512), blk, 0, stream>>>(Wqkv, Wmix, bmix, W1, W2, bmixf);
  wtrans<<<dim3(60), blk, 0, stream>>>(w3, w5, w7, wT3, wT5, wT7);
  // kvmat = x @ Wqkv[512:1536]^T -> bf16 [M,1024]
  gemm_mfma<false, true, false, false, false, false><<<dim3(8, 256), blk, 0, stream>>>(
      x, Wqkv + (size_t)512 * 512, nullptr, nullptr, nullptr, kvmat, 1024);
  // mqb = mx @ Wqkv[0:512]^T -> bf16 [M,512]
  gemm_mfma<false, true, false, false, false, false><<<dim3(4, 256), blk, 0, stream>>>(
      mx, Wqkv, nullptr, nullptr, nullptr, mqb, 512);
  // qmixb = mx @ W1^T + x @ W2^T + bmix -> bf16 [M,512]
  gemm_mfma<false, true, true, true, false, false><<<dim3(4, 256), blk, 0, stream>>>(
      mx, W1, x, W2, bmixf, qmixb, 512);
  zero_colsum<<<dim3(4), blk, 0, stream>>>(colsum);
  kv_mfma<<<dim3(512), blk, 0, stream>>>(kvmat, kvpart, colsum);
  kv_reduce<<<dim3(256), blk, 0, stream>>>(kvpart, kvbuf);
  // Wb[b] = 0.125 * diag(1/colsum) blockdiag(kv[b]) @ Wproj^T  (bf16)
  wproj_eff<<<dim3(1024), blk, 0, stream>>>(kvbuf, Wproj, colsum, Wb);
  // crpe = qmix * dwconv(v), in place over qmixb
  conv_crpe<3, 0, 128, 256><<<dim3(2048), dim3(256), 0, stream>>>(kvmat, qmixb, wT3, b3);
  conv_crpe<5, 128, 192, 192><<<dim3(4096), dim3(192), 0, stream>>>(kvmat, qmixb, wT5, b5);
  conv_crpe<7, 320, 192, 192><<<dim3(4096), dim3(192), 0, stream>>>(kvmat, qmixb, wT7, b7);
  // out = crpe @ Wproj^T + mq @ Wb[b]^T + bproj
  gemm_mfma<true, false, true, true, true, true><<<dim3(4, 256), blk, 0, stream>>>(
      qmixb, Wproj, mqb, Wb, bproj, d_out, 512);
}

// Round 8
// 551.719 us; speedup vs baseline: 3.9590x; 1.1201x over previous
//
#include <hip/hip_runtime.h>
#include <hip/hip_bf16.h>

#define MROWS 32768
#define NSEQ 4096
#define KDIM 512

typedef short sh8 __attribute__((ext_vector_type(8)));
typedef float fx4 __attribute__((ext_vector_type(4)));

__device__ __forceinline__ unsigned short f2bf(float f) {
  union { float f; unsigned u; } v; v.f = f;
  unsigned r = v.u + 0x7FFFu + ((v.u >> 16) & 1u);
  return (unsigned short)(r >> 16);
}
__device__ __forceinline__ float bf2f(unsigned short u) {
  union { unsigned u; float f; } v; v.u = ((unsigned)u) << 16;
  return v.f;
}

// async global->LDS, 16B per lane; lds base must be wave-uniform.
__device__ __forceinline__ void gload16(const unsigned short* g, unsigned short* l) {
  __builtin_amdgcn_global_load_lds(
      (const __attribute__((address_space(1))) unsigned int*)g,
      (__attribute__((address_space(3))) unsigned int*)l, 16, 0, 0);
}

// ---------------------------------------------------------------------------
// bf16 MFMA GEMM: Co[M,Nn] = A@W^T (+ A2@W2^T) (+bias).  K fixed 512.
// 128x128 tile, BK=64, 256 thr = 4 waves (2x2 of 64x64), mfma 16x16x32.
// LDS [128 rows][8 slots of 8 bf16], phys_slot = log_slot ^ (row&7) swizzle.
// W always bf16 via global_load_lds (source pre-swizzled).
// A: bf16 -> global_load_lds; fp32 -> reg-stage+convert at swizzled slots.
// 1-D grid with bijective XCD swizzle; NXL = log2(col-blocks).
// PER_B2: pass-2 weight has per-batch 512x512 slabs (b = by>>5).
// ---------------------------------------------------------------------------
template<bool A_BF16, bool OUT_BF16, bool HAS_BIAS, bool TWO, bool PER_B2, int NXL>
__global__ __launch_bounds__(256) void gemm_bf16(
    const void* Av, const unsigned short* __restrict__ W,
    const void* A2v, const unsigned short* __restrict__ W2,
    const float* __restrict__ bias, void* Co, int Nn) {
  __shared__ unsigned short As[128 * 64];
  __shared__ unsigned short Bs[128 * 64];
  const int tid = threadIdx.x;
  const int lane = tid & 63, wv = tid >> 6;
  const int wr = wv >> 1, wc = wv & 1;
  const int nwg = gridDim.x;
  const int lid = (blockIdx.x & 7) * (nwg >> 3) + (blockIdx.x >> 3);
  const int bx = lid & ((1 << NXL) - 1);
  const int by = lid >> NXL;
  const int fr = lane & 15, fg = lane >> 4;
  const int srow = lane >> 3;   // row within an 8-row staging chunk
  const int sphys = lane & 7;   // physical slot this lane fills
  fx4 acc[4][4] = {};
#pragma unroll
  for (int pass = 0; pass < (TWO ? 2 : 1); ++pass) {
    const unsigned short* Wp = (TWO && pass) ? W2 : W;
    if (TWO && pass && PER_B2) Wp += (size_t)(by >> 5) * (512 * 512);
    const void* Ap = (TWO && pass) ? A2v : Av;
    for (int k0 = 0; k0 < KDIM; k0 += 64) {
      // ---- stage W tile (global_load_lds, inverse-swizzled source) ----
#pragma unroll
      for (int l = 0; l < 4; ++l) {
        int rb = wv * 4 + l;
        int r = rb * 8 + srow;
        int clog = sphys ^ (r & 7);
        gload16(Wp + (size_t)(bx * 128 + r) * KDIM + k0 + clog * 8, &Bs[rb * 512]);
      }
      // ---- stage A tile ----
      if constexpr (A_BF16) {
        const unsigned short* Ab = (const unsigned short*)Ap;
#pragma unroll
        for (int l = 0; l < 4; ++l) {
          int rb = wv * 4 + l;
          int r = rb * 8 + srow;
          int clog = sphys ^ (r & 7);
          gload16(Ab + (size_t)(by * 128 + r) * KDIM + k0 + clog * 8, &As[rb * 512]);
        }
      } else {
        const float* Af = (const float*)Ap;
#pragma unroll
        for (int s = 0; s < 4; ++s) {
          int u = s * 256 + tid;
          int r = u >> 3, cp = u & 7;
          int clog = cp ^ (r & 7);
          const float* src = Af + (size_t)(by * 128 + r) * KDIM + k0 + clog * 8;
          float4 v0 = *reinterpret_cast<const float4*>(src);
          float4 v1 = *reinterpret_cast<const float4*>(src + 4);
          uint4 o;
          o.x = (unsigned)f2bf(v0.x) | ((unsigned)f2bf(v0.y) << 16);
          o.y = (unsigned)f2bf(v0.z) | ((unsigned)f2bf(v0.w) << 16);
          o.z = (unsigned)f2bf(v1.x) | ((unsigned)f2bf(v1.y) << 16);
          o.w = (unsigned)f2bf(v1.z) | ((unsigned)f2bf(v1.w) << 16);
          *reinterpret_cast<uint4*>(&As[r * 64 + cp * 8]) = o;
        }
      }
      __syncthreads();
      // ---- compute: two k=32 substeps ----
#pragma unroll
      for (int ks = 0; ks < 2; ++ks) {
        sh8 a[4], b[4];
#pragma unroll
        for (int m = 0; m < 4; ++m) {
          int r = wr * 64 + m * 16 + fr;
          int p = (ks * 4 + fg) ^ (r & 7);
          a[m] = *reinterpret_cast<const sh8*>(&As[r * 64 + p * 8]);
        }
#pragma unroll
        for (int n = 0; n < 4; ++n) {
          int r = wc * 64 + n * 16 + fr;
          int p = (ks * 4 + fg) ^ (r & 7);
          b[n] = *reinterpret_cast<const sh8*>(&Bs[r * 64 + p * 8]);
        }
#pragma unroll
        for (int m = 0; m < 4; ++m)
#pragma unroll
          for (int n = 0; n < 4; ++n)
            acc[m][n] = __builtin_amdgcn_mfma_f32_16x16x32_bf16(a[m], b[n], acc[m][n], 0, 0, 0);
      }
      __syncthreads();
    }
  }
  unsigned short* Cb = (unsigned short*)Co;
  float* Cf = (float*)Co;
#pragma unroll
  for (int n = 0; n < 4; ++n) {
    int col = bx * 128 + wc * 64 + n * 16 + fr;
    float bb = 0.f;
    if constexpr (HAS_BIAS) bb = bias[col];
#pragma unroll
    for (int m = 0; m < 4; ++m) {
#pragma unroll
      for (int j = 0; j < 4; ++j) {
        int row = by * 128 + wr * 64 + m * 16 + fg * 4 + j;
        float val = acc[m][n][j] + bb;
        if constexpr (OUT_BF16)
          Cb[(size_t)row * Nn + col] = f2bf(val);
        else
          Cf[(size_t)row * Nn + col] = val;
      }
    }
  }
}

// ---------------------------------------------------------------------------
// fp32 -> bf16 bulk convert (8 elems/thread).
// ---------------------------------------------------------------------------
__global__ __launch_bounds__(256) void cvt_bf16(
    const float* __restrict__ src, unsigned short* __restrict__ dst, int n8) {
  int i = blockIdx.x * 256 + threadIdx.x;
  if (i >= n8) return;
  float4 v0 = *reinterpret_cast<const float4*>(src + (size_t)i * 8);
  float4 v1 = *reinterpret_cast<const float4*>(src + (size_t)i * 8 + 4);
  uint4 o;
  o.x = (unsigned)f2bf(v0.x) | ((unsigned)f2bf(v0.y) << 16);
  o.y = (unsigned)f2bf(v0.z) | ((unsigned)f2bf(v0.w) << 16);
  o.z = (unsigned)f2bf(v1.x) | ((unsigned)f2bf(v1.y) << 16);
  o.w = (unsigned)f2bf(v1.z) | ((unsigned)f2bf(v1.w) << 16);
  *reinterpret_cast<uint4*>(dst + (size_t)i * 8) = o;
}

// ---------------------------------------------------------------------------
// Effective mix weights (bf16 out) + bmix broadcast to 512.
// ---------------------------------------------------------------------------
__global__ __launch_bounds__(256) void eff_weights(
    const float* __restrict__ Wqkv, const float* __restrict__ Wmix,
    const float* __restrict__ bmix,
    unsigned short* __restrict__ W1, unsigned short* __restrict__ W2,
    float* __restrict__ bmixfull) {
  int r = blockIdx.x;
  int h = r >> 6, j = r & 63;
  int t = threadIdx.x;
  if (t == 0) bmixfull[r] = bmix[j];
  float a10 = 0.f, a11 = 0.f, a20 = 0.f, a21 = 0.f;
  for (int i = 0; i < 64; ++i) {
    float w1 = Wmix[j * 128 + i], w2 = Wmix[j * 128 + 64 + i];
    const float* wr = Wqkv + (size_t)(h * 64 + i) * KDIM;
    a10 = fmaf(w1, wr[t], a10);
    a11 = fmaf(w1, wr[t + 256], a11);
    a20 = fmaf(w2, wr[t], a20);
    a21 = fmaf(w2, wr[t + 256], a21);
  }
  W1[(size_t)r * KDIM + t] = f2bf(a10);
  W1[(size_t)r * KDIM + t + 256] = f2bf(a11);
  W2[(size_t)r * KDIM + t] = f2bf(a20);
  W2[(size_t)r * KDIM + t + 256] = f2bf(a21);
}

// ---------------------------------------------------------------------------
// Transpose conv weights to tap-major: wT[k*k][CG].
// ---------------------------------------------------------------------------
__global__ __launch_bounds__(256) void wtrans(
    const float* __restrict__ w3, const float* __restrict__ w5,
    const float* __restrict__ w7,
    float* __restrict__ wT3, float* __restrict__ wT5, float* __restrict__ wT7) {
  int i = blockIdx.x * 256 + threadIdx.x;
  if (i < 1152) {
    int ti = i >> 7, c = i & 127;
    wT3[i] = w3[c * 9 + ti];
  } else if (i < 5952) {
    int j = i - 1152;
    int ti = j / 192, c = j - ti * 192;
    wT5[j] = w5[c * 25 + ti];
  } else {
    int j = i - 5952;
    int ti = j / 192, c = j - ti * 192;
    wT7[j] = w7[c * 49 + ti];
  }
}

__global__ __launch_bounds__(256) void zero_colsum(float* __restrict__ p) {
  int i = (blockIdx.x * 256 + threadIdx.x) * 4;
  *reinterpret_cast<float4*>(p + i) = make_float4(0.f, 0.f, 0.f, 0.f);
}

// ---------------------------------------------------------------------------
// kv partials via MFMA (no global atomics on the matrix path).
// ---------------------------------------------------------------------------
__global__ __launch_bounds__(256) void kv_mfma(
    const unsigned short* __restrict__ kvmat,
    float* __restrict__ kvpart, float* __restrict__ colsum) {
  __shared__ unsigned short eK[64][40];
  __shared__ unsigned short eV[64][40];
  __shared__ float cw[4][64];
  int t = threadIdx.x;
  int split = blockIdx.x & 7;
  int bh = blockIdx.x >> 3;
  int h = bh & 7, b = bh >> 3;
  int lane = t & 63, wv = t >> 6;
  int wr = wv >> 1, wc = wv & 1;
  int fr = lane & 15, fg = lane >> 4;
  int cg = t & 7, nl = t >> 3;
  const unsigned short* kb = kvmat + (size_t)b * NSEQ * 1024 + h * 64 + cg * 8;
  const unsigned short* vb = kb + 512;
  int colS = nl ^ ((cg & 3) << 3);
  fx4 acc[2][2] = {};
  float csum[8] = {};
  for (int n0 = split * 512; n0 < split * 512 + 512; n0 += 32) {
    size_t off = (size_t)(n0 + nl) * 1024;
    sh8 k8 = *reinterpret_cast<const sh8*>(kb + off);
    sh8 v8 = *reinterpret_cast<const sh8*>(vb + off);
#pragma unroll
    for (int j = 0; j < 8; ++j) {
      float e = __expf(bf2f((unsigned short)k8[j]));
      csum[j] += e;
      eK[cg * 8 + j][colS] = f2bf(e);
      eV[cg * 8 + j][colS] = (unsigned short)v8[j];
    }
    __syncthreads();
    sh8 a[2], bb[2];
#pragma unroll
    for (int m = 0; m < 2; ++m) {
      int r = wr * 32 + m * 16 + fr;
      int c8 = (fg ^ ((r >> 3) & 3)) * 8;
      a[m] = *reinterpret_cast<const sh8*>(&eK[r][c8]);
    }
#pragma unroll
    for (int n = 0; n < 2; ++n) {
      int r = wc * 32 + n * 16 + fr;
      int c8 = (fg ^ ((r >> 3) & 3)) * 8;
      bb[n] = *reinterpret_cast<const sh8*>(&eV[r][c8]);
    }
#pragma unroll
    for (int m = 0; m < 2; ++m)
#pragma unroll
      for (int n = 0; n < 2; ++n)
        acc[m][n] = __builtin_amdgcn_mfma_f32_16x16x32_bf16(a[m], bb[n], acc[m][n], 0, 0, 0);
    __syncthreads();
  }
  float* kvp = kvpart + (size_t)split * 64 * 4096 + (size_t)bh * 4096;
#pragma unroll
  for (int m = 0; m < 2; ++m)
#pragma unroll
    for (int n = 0; n < 2; ++n)
#pragma unroll
      for (int j = 0; j < 4; ++j) {
        int row = wr * 32 + m * 16 + fg * 4 + j;
        int col = wc * 32 + n * 16 + fr;
        kvp[row * 64 + col] = acc[m][n][j];
      }
#pragma unroll
  for (int j = 0; j < 8; ++j) {
    float v = csum[j];
    v += __shfl_xor(v, 8);
    v += __shfl_xor(v, 16);
    v += __shfl_xor(v, 32);
    csum[j] = v;
  }
  if (lane < 8) {
#pragma unroll
    for (int j = 0; j < 8; ++j) cw[wv][lane * 8 + j] = csum[j];
  }
  __syncthreads();
  if (t < 64) {
    float s = cw[0][t] + cw[1][t] + cw[2][t] + cw[3][t];
    atomicAdd(&colsum[b * 512 + h * 64 + t], s);
  }
}

__global__ __launch_bounds__(256) void kv_reduce(
    const float* __restrict__ kvpart, float* __restrict__ kvbuf) {
  int i = (blockIdx.x * 256 + threadIdx.x) * 4;
  float4 s = make_float4(0.f, 0.f, 0.f, 0.f);
#pragma unroll
  for (int sp = 0; sp < 8; ++sp) {
    float4 v = *reinterpret_cast<const float4*>(kvpart + (size_t)sp * 262144 + i);
    s.x += v.x; s.y += v.y; s.z += v.z; s.w += v.w;
  }
  *reinterpret_cast<float4*>(kvbuf + i) = s;
}

// ---------------------------------------------------------------------------
// Wb[b][j][h*64+ck] = 0.125/colsum * sum_ch kv[b,h,ck,ch]*Wproj[j,h*64+ch]
// ---------------------------------------------------------------------------
__global__ __launch_bounds__(256) void wproj_eff(
    const float* __restrict__ kvbuf, const float* __restrict__ Wproj,
    const float* __restrict__ colsum, unsigned short* __restrict__ Wb) {
  int bid = blockIdx.x;
  int jt = bid & 15, h = (bid >> 4) & 7, b = bid >> 7;
  int j0 = jt * 32;
  __shared__ float kvs[64][65];
  __shared__ float wps[32][64];
  int t = threadIdx.x;
  const float* kvsrc = kvbuf + (size_t)(b * 8 + h) * 4096;
  for (int i = t; i < 4096; i += 256) kvs[i >> 6][i & 63] = kvsrc[i];
  for (int i = t; i < 2048; i += 256)
    wps[i >> 6][i & 63] = Wproj[(size_t)(j0 + (i >> 6)) * 512 + h * 64 + (i & 63)];
  __syncthreads();
  int ck = t & 63, jl = t >> 6;
  float rs = 0.125f / colsum[b * 512 + h * 64 + ck];
  float acc[8] = {};
  for (int ch = 0; ch < 64; ++ch) {
    float kvv = kvs[ck][ch];
#pragma unroll
    for (int g = 0; g < 8; ++g)
      acc[g] = fmaf(kvv, wps[jl * 8 + g][ch], acc[g]);
  }
#pragma unroll
  for (int g = 0; g < 8; ++g)
    Wb[((size_t)b * 512 + j0 + jl * 8 + g) * 512 + h * 64 + ck] = f2bf(rs * acc[g]);
}

// ---------------------------------------------------------------------------
// Depthwise conv + crpe multiply, 8 channels/thread.
// ---------------------------------------------------------------------------
template<int KW, int C0, int CG, int TPB>
__global__ __launch_bounds__(TPB) void conv_crpe(
    const unsigned short* __restrict__ kvmat,
    unsigned short* __restrict__ qmixb,
    const float* __restrict__ wT, const float* __restrict__ bias) {
  constexpr int SLOTS = CG / 8;
  constexpr int ROWS_PB = TPB / SLOTS;
  constexpr int P = KW / 2;
  int t = threadIdx.x;
  int row_local = t / SLOTS;
  int slot = t - row_local * SLOTS;
  int row = blockIdx.x * ROWS_PB + row_local;
  int n = row & 4095, b = row >> 12;
  int y = n >> 6, x = n & 63;
  int cl = slot * 8;
  float acc[8] = {};
  const unsigned short* vb =
      kvmat + (size_t)b * NSEQ * 1024 + 512 + C0 + cl;
#pragma unroll
  for (int dy = 0; dy < KW; ++dy) {
    int yy = y + dy - P;
    if ((unsigned)yy >= 64u) continue;
#pragma unroll
    for (int dx = 0; dx < KW; ++dx) {
      int xq = x + dx - P;
      if ((unsigned)xq >= 64u) continue;
      sh8 v8 = *reinterpret_cast<const sh8*>(vb + (size_t)(yy * 64 + xq) * 1024);
      const float* wp = wT + (dy * KW + dx) * CG + cl;
      float4 w0 = *reinterpret_cast<const float4*>(wp);
      float4 w1 = *reinterpret_cast<const float4*>(wp + 4);
      acc[0] = fmaf(w0.x, bf2f((unsigned short)v8[0]), acc[0]);
      acc[1] = fmaf(w0.y, bf2f((unsigned short)v8[1]), acc[1]);
      acc[2] = fmaf(w0.z, bf2f((unsigned short)v8[2]), acc[2]);
      acc[3] = fmaf(w0.w, bf2f((unsigned short)v8[3]), acc[3]);
      acc[4] = fmaf(w1.x, bf2f((unsigned short)v8[4]), acc[4]);
      acc[5] = fmaf(w1.y, bf2f((unsigned short)v8[5]), acc[5]);
      acc[6] = fmaf(w1.z, bf2f((unsigned short)v8[6]), acc[6]);
      acc[7] = fmaf(w1.w, bf2f((unsigned short)v8[7]), acc[7]);
    }
  }
  float4 b0 = *reinterpret_cast<const float4*>(bias + cl);
  float4 b1 = *reinterpret_cast<const float4*>(bias + cl + 4);
  unsigned short* qp = qmixb + (size_t)row * 512 + C0 + cl;
  sh8 qm = *reinterpret_cast<const sh8*>(qp);
  sh8 out;
  out[0] = (short)f2bf(bf2f((unsigned short)qm[0]) * (acc[0] + b0.x));
  out[1] = (short)f2bf(bf2f((unsigned short)qm[1]) * (acc[1] + b0.y));
  out[2] = (short)f2bf(bf2f((unsigned short)qm[2]) * (acc[2] + b0.z));
  out[3] = (short)f2bf(bf2f((unsigned short)qm[3]) * (acc[3] + b0.w));
  out[4] = (short)f2bf(bf2f((unsigned short)qm[4]) * (acc[4] + b1.x));
  out[5] = (short)f2bf(bf2f((unsigned short)qm[5]) * (acc[5] + b1.y));
  out[6] = (short)f2bf(bf2f((unsigned short)qm[6]) * (acc[6] + b1.z));
  out[7] = (short)f2bf(bf2f((unsigned short)qm[7]) * (acc[7] + b1.w));
  *reinterpret_cast<sh8*>(qp) = out;
}

// ---------------------------------------------------------------------------
extern "C" void kernel_launch(void* const* d_in, const int* in_sizes, int n_in,
                              void* d_out, int out_size, void* d_ws, size_t ws_size,
                              hipStream_t stream) {
  const float* x     = (const float*)d_in[0];
  const float* mx    = (const float*)d_in[1];
  const float* Wqkv  = (const float*)d_in[2];
  const float* Wproj = (const float*)d_in[3];
  const float* bproj = (const float*)d_in[4];
  const float* Wmix  = (const float*)d_in[5];
  const float* bmix  = (const float*)d_in[6];
  const float* w3    = (const float*)d_in[7];
  const float* b3    = (const float*)d_in[8];
  const float* w5    = (const float*)d_in[9];
  const float* b5    = (const float*)d_in[10];
  const float* w7    = (const float*)d_in[11];
  const float* b7    = (const float*)d_in[12];

  // kvmat (bf16 [M,1024], k|v) lives in d_out — dead before proj writes out.
  unsigned short* kvmat = (unsigned short*)d_out;

  char* wsp = (char*)d_ws;
  auto carve = [&wsp](size_t bytes) {
    char* p = wsp;
    wsp += (bytes + 255) & ~(size_t)255;
    return p;
  };
  unsigned short* mqb    = (unsigned short*)carve((size_t)MROWS * 512 * 2);  // 33.5 MB
  unsigned short* qmixb  = (unsigned short*)carve((size_t)MROWS * 512 * 2);  // 33.5 MB
  unsigned short* Wqkvb  = (unsigned short*)carve((size_t)1536 * 512 * 2);   // 1.5 MB
  unsigned short* Wprojb = (unsigned short*)carve((size_t)512 * 512 * 2);
  unsigned short* W1b    = (unsigned short*)carve((size_t)512 * 512 * 2);
  unsigned short* W2b    = (unsigned short*)carve((size_t)512 * 512 * 2);
  float* bmixf  = (float*)carve(512 * 4);
  float* kvbuf  = (float*)carve(8 * 8 * 64 * 64 * 4);   // 1 MB
  float* colsum = (float*)carve(4096 * 4);
  float* wT3    = (float*)carve(9 * 128 * 4);
  float* wT5    = (float*)carve(25 * 192 * 4);
  float* wT7    = (float*)carve(49 * 192 * 4);
  float* kvpart = (float*)carve((size_t)8 * 64 * 4096 * 4);  // 8 MB
  unsigned short* Wb = (unsigned short*)carve((size_t)8 * 512 * 512 * 2);  // 4.2 MB
  // total ~85 MB

  dim3 blk(256);
  eff_weights<<<dim3(512), blk, 0, stream>>>(Wqkv, Wmix, bmix, W1b, W2b, bmixf);
  wtrans<<<dim3(60), blk, 0, stream>>>(w3, w5, w7, wT3, wT5, wT7);
  cvt_bf16<<<dim3(384), blk, 0, stream>>>(Wqkv, Wqkvb, 1536 * 512 / 8);
  cvt_bf16<<<dim3(128), blk, 0, stream>>>(Wproj, Wprojb, 512 * 512 / 8);
  // kvmat = x @ Wqkv[512:1536]^T -> bf16 [M,1024]
  gemm_bf16<false, true, false, false, false, 3><<<dim3(2048), blk, 0, stream>>>(
      x, Wqkvb + (size_t)512 * 512, nullptr, nullptr, nullptr, kvmat, 1024);
  // mqb = mx @ Wqkv[0:512]^T -> bf16 [M,512]
  gemm_bf16<false, true, false, false, false, 2><<<dim3(1024), blk, 0, stream>>>(
      mx, Wqkvb, nullptr, nullptr, nullptr, mqb, 512);
  // qmixb = mx @ W1^T + x @ W2^T + bmix -> bf16 [M,512]
  gemm_bf16<false, true, true, true, false, 2><<<dim3(1024), blk, 0, stream>>>(
      mx, W1b, x, W2b, bmixf, qmixb, 512);
  zero_colsum<<<dim3(4), blk, 0, stream>>>(colsum);
  kv_mfma<<<dim3(512), blk, 0, stream>>>(kvmat, kvpart, colsum);
  kv_reduce<<<dim3(256), blk, 0, stream>>>(kvpart, kvbuf);
  wproj_eff<<<dim3(1024), blk, 0, stream>>>(kvbuf, Wproj, colsum, Wb);
  // crpe = qmix * dwconv(v), in place over qmixb
  conv_crpe<3, 0, 128, 256><<<dim3(2048), dim3(256), 0, stream>>>(kvmat, qmixb, wT3, b3);
  conv_crpe<5, 128, 192, 192><<<dim3(4096), dim3(192), 0, stream>>>(kvmat, qmixb, wT5, b5);
  conv_crpe<7, 320, 192, 192><<<dim3(4096), dim3(192), 0, stream>>>(kvmat, qmixb, wT7, b7);
  // out = crpe @ Wproj^T + mq @ Wb[b]^T + bproj
  gemm_bf16<true, false, true, true, true, 2><<<dim3(1024), blk, 0, stream>>>(
      qmixb, Wprojb, mqb, Wb, bproj, d_out, 512);
}

// Round 10
// 511.350 us; speedup vs baseline: 4.2716x; 1.0789x over previous
//
#include <hip/hip_runtime.h>
#include <hip/hip_bf16.h>

#define MROWS 32768
#define NSEQ 4096
#define KDIM 512

typedef short sh8 __attribute__((ext_vector_type(8)));
typedef float fx4 __attribute__((ext_vector_type(4)));

__device__ __forceinline__ unsigned short f2bf(float f) {
  union { float f; unsigned u; } v; v.f = f;
  unsigned r = v.u + 0x7FFFu + ((v.u >> 16) & 1u);
  return (unsigned short)(r >> 16);
}
__device__ __forceinline__ float bf2f(unsigned short u) {
  union { unsigned u; float f; } v; v.u = ((unsigned)u) << 16;
  return v.f;
}

// async global->LDS, 16B per lane; lds base must be wave-uniform.
__device__ __forceinline__ void gload16(const unsigned short* g, unsigned short* l) {
  __builtin_amdgcn_global_load_lds(
      (const __attribute__((address_space(1))) unsigned int*)g,
      (__attribute__((address_space(3))) unsigned int*)l, 16, 0, 0);
}

// ---------------------------------------------------------------------------
// bf16 MFMA GEMM: Co[M,Nn] = A@W^T (+ A2@W2^T) (+bias).  K fixed 512.
// 128x128 tile, BK=32 (m97 structure: 16 KB LDS, 16 MFMA + 8 ds_read_b128 +
// 2 gload16/thread per K-step), 256 thr = 4 waves (2x2 of 64x64).
// LDS [128 rows][4 slots of 8 bf16], phys_slot = log_slot ^ (row&3) swizzle.
// A bf16 -> global_load_lds (pre-swizzled source); fp32 -> reg-stage+convert.
// 1-D grid with bijective XCD swizzle; NXL = log2(col-blocks).
// PER_B2: pass-2 weight has per-batch 512x512 slabs (b = by>>5).
// ---------------------------------------------------------------------------
template<bool A_BF16, bool OUT_BF16, bool HAS_BIAS, bool TWO, bool PER_B2, int NXL>
__global__ __launch_bounds__(256) void gemm_bf16(
    const void* Av, const unsigned short* __restrict__ W,
    const void* A2v, const unsigned short* __restrict__ W2,
    const float* __restrict__ bias, void* Co, int Nn) {
  __shared__ unsigned short As[128 * 32];
  __shared__ unsigned short Bs[128 * 32];
  const int tid = threadIdx.x;
  const int lane = tid & 63, wv = tid >> 6;
  const int wr = wv >> 1, wc = wv & 1;
  const int nwg = gridDim.x;
  const int lid = (blockIdx.x & 7) * (nwg >> 3) + (blockIdx.x >> 3);
  const int bx = lid & ((1 << NXL) - 1);
  const int by = lid >> NXL;
  const int fr = lane & 15, fg = lane >> 4;
  fx4 acc[4][4] = {};
#pragma unroll
  for (int pass = 0; pass < (TWO ? 2 : 1); ++pass) {
    const unsigned short* Wp = (TWO && pass) ? W2 : W;
    if (TWO && pass && PER_B2) Wp += (size_t)(by >> 5) * (512 * 512);
    const void* Ap = (TWO && pass) ? A2v : Av;
    for (int k0 = 0; k0 < KDIM; k0 += 32) {
      // ---- stage W tile: 8 chunks of 16 rows, 1 KB per wave-instruction ----
#pragma unroll
      for (int l = 0; l < 2; ++l) {
        int chunk = wv * 2 + l;
        int r = chunk * 16 + (lane >> 2);
        int clog = (lane & 3) ^ (r & 3);
        gload16(Wp + (size_t)(bx * 128 + r) * KDIM + k0 + clog * 8, &Bs[chunk * 512]);
      }
      // ---- stage A tile ----
      if constexpr (A_BF16) {
        const unsigned short* Ab = (const unsigned short*)Ap;
#pragma unroll
        for (int l = 0; l < 2; ++l) {
          int chunk = wv * 2 + l;
          int r = chunk * 16 + (lane >> 2);
          int clog = (lane & 3) ^ (r & 3);
          gload16(Ab + (size_t)(by * 128 + r) * KDIM + k0 + clog * 8, &As[chunk * 512]);
        }
      } else {
        const float* Af = (const float*)Ap;
#pragma unroll
        for (int s = 0; s < 2; ++s) {
          int u = s * 256 + tid;
          int r = u >> 2, cp = u & 3;
          int clog = cp ^ (r & 3);
          const float* src = Af + (size_t)(by * 128 + r) * KDIM + k0 + clog * 8;
          float4 v0 = *reinterpret_cast<const float4*>(src);
          float4 v1 = *reinterpret_cast<const float4*>(src + 4);
          uint4 o;
          o.x = (unsigned)f2bf(v0.x) | ((unsigned)f2bf(v0.y) << 16);
          o.y = (unsigned)f2bf(v0.z) | ((unsigned)f2bf(v0.w) << 16);
          o.z = (unsigned)f2bf(v1.x) | ((unsigned)f2bf(v1.y) << 16);
          o.w = (unsigned)f2bf(v1.z) | ((unsigned)f2bf(v1.w) << 16);
          *reinterpret_cast<uint4*>(&As[r * 32 + cp * 8]) = o;
        }
      }
      __syncthreads();
      // ---- compute: 16 MFMA per K-step ----
      sh8 a[4], b[4];
#pragma unroll
      for (int m = 0; m < 4; ++m) {
        int r = wr * 64 + m * 16 + fr;
        int p = fg ^ (r & 3);
        a[m] = *reinterpret_cast<const sh8*>(&As[r * 32 + p * 8]);
      }
#pragma unroll
      for (int n = 0; n < 4; ++n) {
        int r = wc * 64 + n * 16 + fr;
        int p = fg ^ (r & 3);
        b[n] = *reinterpret_cast<const sh8*>(&Bs[r * 32 + p * 8]);
      }
#pragma unroll
      for (int m = 0; m < 4; ++m)
#pragma unroll
        for (int n = 0; n < 4; ++n)
          acc[m][n] = __builtin_amdgcn_mfma_f32_16x16x32_bf16(a[m], b[n], acc[m][n], 0, 0, 0);
      __syncthreads();
    }
  }
  unsigned short* Cb = (unsigned short*)Co;
  float* Cf = (float*)Co;
#pragma unroll
  for (int n = 0; n < 4; ++n) {
    int col = bx * 128 + wc * 64 + n * 16 + fr;
    float bb = 0.f;
    if constexpr (HAS_BIAS) bb = bias[col];
#pragma unroll
    for (int m = 0; m < 4; ++m) {
#pragma unroll
      for (int j = 0; j < 4; ++j) {
        int row = by * 128 + wr * 64 + m * 16 + fg * 4 + j;
        float val = acc[m][n][j] + bb;
        if constexpr (OUT_BF16)
          Cb[(size_t)row * Nn + col] = f2bf(val);
        else
          Cf[(size_t)row * Nn + col] = val;
      }
    }
  }
}

// ---------------------------------------------------------------------------
// fp32 -> bf16 bulk convert (8 elems/thread).
// ---------------------------------------------------------------------------
__global__ __launch_bounds__(256) void cvt_bf16(
    const float* __restrict__ src, unsigned short* __restrict__ dst, int n8) {
  int i = blockIdx.x * 256 + threadIdx.x;
  if (i >= n8) return;
  float4 v0 = *reinterpret_cast<const float4*>(src + (size_t)i * 8);
  float4 v1 = *reinterpret_cast<const float4*>(src + (size_t)i * 8 + 4);
  uint4 o;
  o.x = (unsigned)f2bf(v0.x) | ((unsigned)f2bf(v0.y) << 16);
  o.y = (unsigned)f2bf(v0.z) | ((unsigned)f2bf(v0.w) << 16);
  o.z = (unsigned)f2bf(v1.x) | ((unsigned)f2bf(v1.y) << 16);
  o.w = (unsigned)f2bf(v1.z) | ((unsigned)f2bf(v1.w) << 16);
  *reinterpret_cast<uint4*>(dst + (size_t)i * 8) = o;
}

// ---------------------------------------------------------------------------
// Effective mix weights (bf16 out) + bmix broadcast to 512.
// ---------------------------------------------------------------------------
__global__ __launch_bounds__(256) void eff_weights(
    const float* __restrict__ Wqkv, const float* __restrict__ Wmix,
    const float* __restrict__ bmix,
    unsigned short* __restrict__ W1, unsigned short* __restrict__ W2,
    float* __restrict__ bmixfull) {
  int r = blockIdx.x;
  int h = r >> 6, j = r & 63;
  int t = threadIdx.x;
  if (t == 0) bmixfull[r] = bmix[j];
  float a10 = 0.f, a11 = 0.f, a20 = 0.f, a21 = 0.f;
  for (int i = 0; i < 64; ++i) {
    float w1 = Wmix[j * 128 + i], w2 = Wmix[j * 128 + 64 + i];
    const float* wr = Wqkv + (size_t)(h * 64 + i) * KDIM;
    a10 = fmaf(w1, wr[t], a10);
    a11 = fmaf(w1, wr[t + 256], a11);
    a20 = fmaf(w2, wr[t], a20);
    a21 = fmaf(w2, wr[t + 256], a21);
  }
  W1[(size_t)r * KDIM + t] = f2bf(a10);
  W1[(size_t)r * KDIM + t + 256] = f2bf(a11);
  W2[(size_t)r * KDIM + t] = f2bf(a20);
  W2[(size_t)r * KDIM + t + 256] = f2bf(a21);
}

// ---------------------------------------------------------------------------
// Transpose conv weights to tap-major: wT[k*k][CG].
// ---------------------------------------------------------------------------
__global__ __launch_bounds__(256) void wtrans(
    const float* __restrict__ w3, const float* __restrict__ w5,
    const float* __restrict__ w7,
    float* __restrict__ wT3, float* __restrict__ wT5, float* __restrict__ wT7) {
  int i = blockIdx.x * 256 + threadIdx.x;
  if (i < 1152) {
    int ti = i >> 7, c = i & 127;
    wT3[i] = w3[c * 9 + ti];
  } else if (i < 5952) {
    int j = i - 1152;
    int ti = j / 192, c = j - ti * 192;
    wT5[j] = w5[c * 25 + ti];
  } else {
    int j = i - 5952;
    int ti = j / 192, c = j - ti * 192;
    wT7[j] = w7[c * 49 + ti];
  }
}

__global__ __launch_bounds__(256) void zero_colsum(float* __restrict__ p) {
  int i = (blockIdx.x * 256 + threadIdx.x) * 4;
  *reinterpret_cast<float4*>(p + i) = make_float4(0.f, 0.f, 0.f, 0.f);
}

// ---------------------------------------------------------------------------
// kv partials via MFMA (no global atomics on the matrix path).
// ---------------------------------------------------------------------------
__global__ __launch_bounds__(256) void kv_mfma(
    const unsigned short* __restrict__ kvmat,
    float* __restrict__ kvpart, float* __restrict__ colsum) {
  __shared__ unsigned short eK[64][40];
  __shared__ unsigned short eV[64][40];
  __shared__ float cw[4][64];
  int t = threadIdx.x;
  int split = blockIdx.x & 7;
  int bh = blockIdx.x >> 3;
  int h = bh & 7, b = bh >> 3;
  int lane = t & 63, wv = t >> 6;
  int wr = wv >> 1, wc = wv & 1;
  int fr = lane & 15, fg = lane >> 4;
  int cg = t & 7, nl = t >> 3;
  const unsigned short* kb = kvmat + (size_t)b * NSEQ * 1024 + h * 64 + cg * 8;
  const unsigned short* vb = kb + 512;
  int colS = nl ^ ((cg & 3) << 3);
  fx4 acc[2][2] = {};
  float csum[8] = {};
  for (int n0 = split * 512; n0 < split * 512 + 512; n0 += 32) {
    size_t off = (size_t)(n0 + nl) * 1024;
    sh8 k8 = *reinterpret_cast<const sh8*>(kb + off);
    sh8 v8 = *reinterpret_cast<const sh8*>(vb + off);
#pragma unroll
    for (int j = 0; j < 8; ++j) {
      float e = __expf(bf2f((unsigned short)k8[j]));
      csum[j] += e;
      eK[cg * 8 + j][colS] = f2bf(e);
      eV[cg * 8 + j][colS] = (unsigned short)v8[j];
    }
    __syncthreads();
    sh8 a[2], bb[2];
#pragma unroll
    for (int m = 0; m < 2; ++m) {
      int r = wr * 32 + m * 16 + fr;
      int c8 = (fg ^ ((r >> 3) & 3)) * 8;
      a[m] = *reinterpret_cast<const sh8*>(&eK[r][c8]);
    }
#pragma unroll
    for (int n = 0; n < 2; ++n) {
      int r = wc * 32 + n * 16 + fr;
      int c8 = (fg ^ ((r >> 3) & 3)) * 8;
      bb[n] = *reinterpret_cast<const sh8*>(&eV[r][c8]);
    }
#pragma unroll
    for (int m = 0; m < 2; ++m)
#pragma unroll
      for (int n = 0; n < 2; ++n)
        acc[m][n] = __builtin_amdgcn_mfma_f32_16x16x32_bf16(a[m], bb[n], acc[m][n], 0, 0, 0);
    __syncthreads();
  }
  float* kvp = kvpart + (size_t)split * 64 * 4096 + (size_t)bh * 4096;
#pragma unroll
  for (int m = 0; m < 2; ++m)
#pragma unroll
    for (int n = 0; n < 2; ++n)
#pragma unroll
      for (int j = 0; j < 4; ++j) {
        int row = wr * 32 + m * 16 + fg * 4 + j;
        int col = wc * 32 + n * 16 + fr;
        kvp[row * 64 + col] = acc[m][n][j];
      }
#pragma unroll
  for (int j = 0; j < 8; ++j) {
    float v = csum[j];
    v += __shfl_xor(v, 8);
    v += __shfl_xor(v, 16);
    v += __shfl_xor(v, 32);
    csum[j] = v;
  }
  if (lane < 8) {
#pragma unroll
    for (int j = 0; j < 8; ++j) cw[wv][lane * 8 + j] = csum[j];
  }
  __syncthreads();
  if (t < 64) {
    float s = cw[0][t] + cw[1][t] + cw[2][t] + cw[3][t];
    atomicAdd(&colsum[b * 512 + h * 64 + t], s);
  }
}

__global__ __launch_bounds__(256) void kv_reduce(
    const float* __restrict__ kvpart, float* __restrict__ kvbuf) {
  int i = (blockIdx.x * 256 + threadIdx.x) * 4;
  float4 s = make_float4(0.f, 0.f, 0.f, 0.f);
#pragma unroll
  for (int sp = 0; sp < 8; ++sp) {
    float4 v = *reinterpret_cast<const float4*>(kvpart + (size_t)sp * 262144 + i);
    s.x += v.x; s.y += v.y; s.z += v.z; s.w += v.w;
  }
  *reinterpret_cast<float4*>(kvbuf + i) = s;
}

// ---------------------------------------------------------------------------
// Wb[b][j][h*64+ck] = 0.125/colsum * sum_ch kv[b,h,ck,ch]*Wproj[j,h*64+ch]
// ---------------------------------------------------------------------------
__global__ __launch_bounds__(256) void wproj_eff(
    const float* __restrict__ kvbuf, const float* __restrict__ Wproj,
    const float* __restrict__ colsum, unsigned short* __restrict__ Wb) {
  int bid = blockIdx.x;
  int jt = bid & 15, h = (bid >> 4) & 7, b = bid >> 7;
  int j0 = jt * 32;
  __shared__ float kvs[64][65];
  __shared__ float wps[32][64];
  int t = threadIdx.x;
  const float* kvsrc = kvbuf + (size_t)(b * 8 + h) * 4096;
  for (int i = t; i < 4096; i += 256) kvs[i >> 6][i & 63] = kvsrc[i];
  for (int i = t; i < 2048; i += 256)
    wps[i >> 6][i & 63] = Wproj[(size_t)(j0 + (i >> 6)) * 512 + h * 64 + (i & 63)];
  __syncthreads();
  int ck = t & 63, jl = t >> 6;
  float rs = 0.125f / colsum[b * 512 + h * 64 + ck];
  float acc[8] = {};
  for (int ch = 0; ch < 64; ++ch) {
    float kvv = kvs[ck][ch];
#pragma unroll
    for (int g = 0; g < 8; ++g)
      acc[g] = fmaf(kvv, wps[jl * 8 + g][ch], acc[g]);
  }
#pragma unroll
  for (int g = 0; g < 8; ++g)
    Wb[((size_t)b * 512 + j0 + jl * 8 + g) * 512 + h * 64 + ck] = f2bf(rs * acc[g]);
}

// ---------------------------------------------------------------------------
// Depthwise conv + crpe multiply, 8 channels/thread.
// ---------------------------------------------------------------------------
template<int KW, int C0, int CG, int TPB>
__global__ __launch_bounds__(TPB) void conv_crpe(
    const unsigned short* __restrict__ kvmat,
    unsigned short* __restrict__ qmixb,
    const float* __restrict__ wT, const float* __restrict__ bias) {
  constexpr int SLOTS = CG / 8;
  constexpr int ROWS_PB = TPB / SLOTS;
  constexpr int P = KW / 2;
  int t = threadIdx.x;
  int row_local = t / SLOTS;
  int slot = t - row_local * SLOTS;
  int row = blockIdx.x * ROWS_PB + row_local;
  int n = row & 4095, b = row >> 12;
  int y = n >> 6, x = n & 63;
  int cl = slot * 8;
  float acc[8] = {};
  const unsigned short* vb =
      kvmat + (size_t)b * NSEQ * 1024 + 512 + C0 + cl;
#pragma unroll
  for (int dy = 0; dy < KW; ++dy) {
    int yy = y + dy - P;
    if ((unsigned)yy >= 64u) continue;
#pragma unroll
    for (int dx = 0; dx < KW; ++dx) {
      int xq = x + dx - P;
      if ((unsigned)xq >= 64u) continue;
      sh8 v8 = *reinterpret_cast<const sh8*>(vb + (size_t)(yy * 64 + xq) * 1024);
      const float* wp = wT + (dy * KW + dx) * CG + cl;
      float4 w0 = *reinterpret_cast<const float4*>(wp);
      float4 w1 = *reinterpret_cast<const float4*>(wp + 4);
      acc[0] = fmaf(w0.x, bf2f((unsigned short)v8[0]), acc[0]);
      acc[1] = fmaf(w0.y, bf2f((unsigned short)v8[1]), acc[1]);
      acc[2] = fmaf(w0.z, bf2f((unsigned short)v8[2]), acc[2]);
      acc[3] = fmaf(w0.w, bf2f((unsigned short)v8[3]), acc[3]);
      acc[4] = fmaf(w1.x, bf2f((unsigned short)v8[4]), acc[4]);
      acc[5] = fmaf(w1.y, bf2f((unsigned short)v8[5]), acc[5]);
      acc[6] = fmaf(w1.z, bf2f((unsigned short)v8[6]), acc[6]);
      acc[7] = fmaf(w1.w, bf2f((unsigned short)v8[7]), acc[7]);
    }
  }
  float4 b0 = *reinterpret_cast<const float4*>(bias + cl);
  float4 b1 = *reinterpret_cast<const float4*>(bias + cl + 4);
  unsigned short* qp = qmixb + (size_t)row * 512 + C0 + cl;
  sh8 qm = *reinterpret_cast<const sh8*>(qp);
  sh8 out;
  out[0] = (short)f2bf(bf2f((unsigned short)qm[0]) * (acc[0] + b0.x));
  out[1] = (short)f2bf(bf2f((unsigned short)qm[1]) * (acc[1] + b0.y));
  out[2] = (short)f2bf(bf2f((unsigned short)qm[2]) * (acc[2] + b0.z));
  out[3] = (short)f2bf(bf2f((unsigned short)qm[3]) * (acc[3] + b0.w));
  out[4] = (short)f2bf(bf2f((unsigned short)qm[4]) * (acc[4] + b1.x));
  out[5] = (short)f2bf(bf2f((unsigned short)qm[5]) * (acc[5] + b1.y));
  out[6] = (short)f2bf(bf2f((unsigned short)qm[6]) * (acc[6] + b1.z));
  out[7] = (short)f2bf(bf2f((unsigned short)qm[7]) * (acc[7] + b1.w));
  *reinterpret_cast<sh8*>(qp) = out;
}

// ---------------------------------------------------------------------------
extern "C" void kernel_launch(void* const* d_in, const int* in_sizes, int n_in,
                              void* d_out, int out_size, void* d_ws, size_t ws_size,
                              hipStream_t stream) {
  const float* x     = (const float*)d_in[0];
  const float* mx    = (const float*)d_in[1];
  const float* Wqkv  = (const float*)d_in[2];
  const float* Wproj = (const float*)d_in[3];
  const float* bproj = (const float*)d_in[4];
  const float* Wmix  = (const float*)d_in[5];
  const float* bmix  = (const float*)d_in[6];
  const float* w3    = (const float*)d_in[7];
  const float* b3    = (const float*)d_in[8];
  const float* w5    = (const float*)d_in[9];
  const float* b5    = (const float*)d_in[10];
  const float* w7    = (const float*)d_in[11];
  const float* b7    = (const float*)d_in[12];

  // kvmat (bf16 [M,1024], k|v) lives in d_out — dead before proj writes out.
  unsigned short* kvmat = (unsigned short*)d_out;

  char* wsp = (char*)d_ws;
  auto carve = [&wsp](size_t bytes) {
    char* p = wsp;
    wsp += (bytes + 255) & ~(size_t)255;
    return p;
  };
  unsigned short* mqb    = (unsigned short*)carve((size_t)MROWS * 512 * 2);  // 33.5 MB
  unsigned short* qmixb  = (unsigned short*)carve((size_t)MROWS * 512 * 2);  // 33.5 MB
  unsigned short* Wqkvb  = (unsigned short*)carve((size_t)1536 * 512 * 2);   // 1.5 MB
  unsigned short* Wprojb = (unsigned short*)carve((size_t)512 * 512 * 2);
  unsigned short* W1b    = (unsigned short*)carve((size_t)512 * 512 * 2);
  unsigned short* W2b    = (unsigned short*)carve((size_t)512 * 512 * 2);
  float* bmixf  = (float*)carve(512 * 4);
  float* kvbuf  = (float*)carve(8 * 8 * 64 * 64 * 4);   // 1 MB
  float* colsum = (float*)carve(4096 * 4);
  float* wT3    = (float*)carve(9 * 128 * 4);
  float* wT5    = (float*)carve(25 * 192 * 4);
  float* wT7    = (float*)carve(49 * 192 * 4);
  float* kvpart = (float*)carve((size_t)8 * 64 * 4096 * 4);  // 8 MB
  unsigned short* Wb = (unsigned short*)carve((size_t)8 * 512 * 512 * 2);  // 4.2 MB
  // base total ~85 MB; optional bf16 copies of x/mx (+67 MB), ws-guarded:
  unsigned short* xb  = (unsigned short*)carve((size_t)MROWS * 512 * 2);
  unsigned short* mxb = (unsigned short*)carve((size_t)MROWS * 512 * 2);
  const bool use16 = (size_t)(wsp - (char*)d_ws) <= ws_size;

  dim3 blk(256);
  eff_weights<<<dim3(512), blk, 0, stream>>>(Wqkv, Wmix, bmix, W1b, W2b, bmixf);
  wtrans<<<dim3(60), blk, 0, stream>>>(w3, w5, w7, wT3, wT5, wT7);
  cvt_bf16<<<dim3(384), blk, 0, stream>>>(Wqkv, Wqkvb, 1536 * 512 / 8);
  cvt_bf16<<<dim3(128), blk, 0, stream>>>(Wproj, Wprojb, 512 * 512 / 8);
  if (use16) {
    cvt_bf16<<<dim3(8192), blk, 0, stream>>>(x, xb, MROWS * 512 / 8);
    cvt_bf16<<<dim3(8192), blk, 0, stream>>>(mx, mxb, MROWS * 512 / 8);
    // kvmat = x @ Wqkv[512:1536]^T -> bf16 [M,1024]
    gemm_bf16<true, true, false, false, false, 3><<<dim3(2048), blk, 0, stream>>>(
        xb, Wqkvb + (size_t)512 * 512, nullptr, nullptr, nullptr, kvmat, 1024);
    // mqb = mx @ Wqkv[0:512]^T -> bf16 [M,512]
    gemm_bf16<true, true, false, false, false, 2><<<dim3(1024), blk, 0, stream>>>(
        mxb, Wqkvb, nullptr, nullptr, nullptr, mqb, 512);
    // qmixb = mx @ W1^T + x @ W2^T + bmix -> bf16 [M,512]
    gemm_bf16<true, true, true, true, false, 2><<<dim3(1024), blk, 0, stream>>>(
        mxb, W1b, xb, W2b, bmixf, qmixb, 512);
  } else {
    gemm_bf16<false, true, false, false, false, 3><<<dim3(2048), blk, 0, stream>>>(
        x, Wqkvb + (size_t)512 * 512, nullptr, nullptr, nullptr, kvmat, 1024);
    gemm_bf16<false, true, false, false, false, 2><<<dim3(1024), blk, 0, stream>>>(
        mx, Wqkvb, nullptr, nullptr, nullptr, mqb, 512);
    gemm_bf16<false, true, true, true, false, 2><<<dim3(1024), blk, 0, stream>>>(
        mx, W1b, x, W2b, bmixf, qmixb, 512);
  }
  zero_colsum<<<dim3(4), blk, 0, stream>>>(colsum);
  kv_mfma<<<dim3(512), blk, 0, stream>>>(kvmat, kvpart, colsum);
  kv_reduce<<<dim3(256), blk, 0, stream>>>(kvpart, kvbuf);
  wproj_eff<<<dim3(1024), blk, 0, stream>>>(kvbuf, Wproj, colsum, Wb);
  // crpe = qmix * dwconv(v), in place over qmixb
  conv_crpe<3, 0, 128, 256><<<dim3(2048), dim3(256), 0, stream>>>(kvmat, qmixb, wT3, b3);
  conv_crpe<5, 128, 192, 192><<<dim3(4096), dim3(192), 0, stream>>>(kvmat, qmixb, wT5, b5);
  conv_crpe<7, 320, 192, 192><<<dim3(4096), dim3(192), 0, stream>>>(kvmat, qmixb, wT7, b7);
  // out = crpe @ Wproj^T + mq @ Wb[b]^T + bproj
  gemm_bf16<true, false, true, true, true, 2><<<dim3(1024), blk, 0, stream>>>(
      qmixb, Wprojb, mqb, Wb, bproj, d_out, 512);
}